// Round 10
// baseline (1697.606 us; speedup 1.0000x reference)
//
#include <hip/hip_runtime.h>
#include <math.h>

typedef float  f32x4  __attribute__((ext_vector_type(4)));
typedef float  f32x2  __attribute__((ext_vector_type(2)));
typedef short  short8v __attribute__((ext_vector_type(8)));
typedef unsigned short ushort8v __attribute__((ext_vector_type(8)));
typedef unsigned short ushort2v __attribute__((ext_vector_type(2)));

#define KP_PRE 3840
#define KP_HS  1536

#define WAITV(N) asm volatile("s_waitcnt vmcnt(" #N ")" ::: "memory")
#define SBAR()   asm volatile("s_barrier" ::: "memory")

// ---------------- persistent device state ----------------------------------
__device__ unsigned short g_Xb[16384][3840];  // pre A (x split-6, swizzled)
__device__ unsigned short g_Wb[2048][3840];   // pre B^T (kernel split-6)
__device__ unsigned short g_Rb[2048][1536];   // z   B^T (rec_kernel, 3 j-splits)
__device__ unsigned short g_hs[2][512][1536]; // h 3 i-splits, ping-pong (nt-stored)
__device__ float g_pre[16384][2048];          // x@K + bias (gate-interleaved)
__device__ float g_hf[2][512 * 512];          // h f32, ping-pong (nt-stored)
__device__ float g_swT[128][512];             // softmax_w transposed
__device__ float g_bperm[2048];               // bias, gate-interleaved cols
__device__ float g_plv[2][512 * 8];           // nt-stored
__device__ int   g_pli[2][512 * 8];           // nt-stored
__device__ unsigned g_xcnt[128];              // 8 per-XCD arrival counters
__device__ unsigned g_pcnt[256];              // 4 pair counters (XCD leaders)
__device__ unsigned g_prel[256];              // 4 pair releases

__global__ void init_counters()
{
    int t = threadIdx.x;
    if (t < 8) g_xcnt[t * 16] = 0u;
    if (t < 4) { g_pcnt[t * 64] = 0u; g_prel[t * 64] = 0u; }
}

// ---------------- helpers ---------------------------------------------------
__device__ __forceinline__ unsigned short f2bf(float f) {
    unsigned u = __float_as_uint(f);
    return (unsigned short)((u + 0x7fffu + ((u >> 16) & 1u)) >> 16);
}
__device__ __forceinline__ float bf2f(unsigned short s) {
    return __uint_as_float(((unsigned)s) << 16);
}
__device__ __forceinline__ float sigf(float x) { return 1.f / (1.f + expf(-x)); }

__device__ __forceinline__ void split3(float v, unsigned short& s0,
                                       unsigned short& s1, unsigned short& s2) {
    s0 = f2bf(v); float f0 = bf2f(s0);
    s1 = f2bf(v - f0); float f1 = bf2f(s1);
    s2 = f2bf(v - f0 - f1);
}

// pair tables: products split_i(A) * split_j(B), i+j <= 2
__device__ __constant__ int c_ipt[6] = {0, 0, 1, 0, 1, 2};
__device__ __constant__ int c_jpt[6] = {0, 1, 0, 2, 1, 0};

__device__ __forceinline__ void gl16(const unsigned short* g, unsigned short* l) {
    __builtin_amdgcn_global_load_lds((const __attribute__((address_space(1))) void*)g,
                                     (__attribute__((address_space(3))) void*)l, 16, 0, 0);
}

// LDS tile: [rows][64] bf16, row = 128B, 16B-units XOR-swizzled by (row&7)
__device__ __forceinline__ short8v fragld(const unsigned short* sh, int row, int uw) {
    return *(const short8v*)(sh + row * 64 + ((uw ^ (row & 7)) << 3));
}

// stage one BK=64 chunk into ring slot: A = AUNITS*16B, B = BUNITS*16B (pre path)
template<int AUNITS, int BUNITS>
__device__ __forceinline__ void stage_chunk(const unsigned short* Ag, int pitchA,
                                            const unsigned short* Bg, int pitchB,
                                            int kb, unsigned short* slot, int tid)
{
#pragma unroll
    for (int v = 0; v < AUNITS / 256; ++v) {
        int e = v * 256 + tid;
        gl16(Ag + (size_t)(e >> 3) * pitchA + kb * 64 + (e & 7) * 8, slot + e * 8);
    }
#pragma unroll
    for (int v = 0; v < BUNITS / 256; ++v) {
        int e = v * 256 + tid;
        gl16(Bg + (size_t)(e >> 3) * pitchB + kb * 64 + (e & 7) * 8,
             slot + AUNITS * 8 + e * 8);
    }
}

// z-path staging, 512-thread variant: one gl16 per split per thread
__device__ __forceinline__ void stageA3w(const unsigned short* Ag, int kr,
                                         unsigned short* buf, int tid)
{
#pragma unroll
    for (int s = 0; s < 3; ++s) {
        int e = tid;   // 0..511 = 64 rows x 8 units
        gl16(Ag + (size_t)(e >> 3) * KP_HS + (s * 8 + kr) * 64 + (e & 7) * 8,
             buf + s * 4096 + e * 8);
    }
}
__device__ __forceinline__ void stageB3w(const unsigned short* Bg, int kr,
                                         unsigned short* buf, int tid)
{
#pragma unroll
    for (int s = 0; s < 3; ++s) {
        int e = tid;
        gl16(Bg + (size_t)(e >> 3) * KP_HS + (s * 8 + kr) * 64 + (e & 7) * 8,
             buf + 12288 + s * 4096 + e * 8);
    }
}
__device__ __forceinline__ void stage6w(const unsigned short* Ag,
                                        const unsigned short* Bg,
                                        int kr, unsigned short* buf, int tid)
{
    stageA3w(Ag, kr, buf, tid);
    stageB3w(Bg, kr, buf, tid);
}

// ---------------- builders (proven R5) --------------------------------------
__global__ __launch_bounds__(256) void build_Xb(const float* __restrict__ fp,
                                                const float* __restrict__ gt)
{
    const int tid = threadIdx.x;
    const int m  = blockIdx.x * 16 + (tid >> 4);
    const int k8 = (blockIdx.y * 16 + (tid & 15)) * 8;
    const int t = m >> 9, b = m & 511;
    float x[8];
    if (k8 < 512) {
        float4 v0 = *(const float4*)(fp + ((size_t)(b * 32 + t)) * 512 + k8);
        float4 v1 = *(const float4*)(fp + ((size_t)(b * 32 + t)) * 512 + k8 + 4);
        x[0]=v0.x; x[1]=v0.y; x[2]=v0.z; x[3]=v0.w;
        x[4]=v1.x; x[5]=v1.y; x[6]=v1.z; x[7]=v1.w;
    } else if (t > 0) {
        float4 v0 = *(const float4*)(gt + ((size_t)(b * 32 + t - 1)) * 128 + (k8 - 512));
        float4 v1 = *(const float4*)(gt + ((size_t)(b * 32 + t - 1)) * 128 + (k8 - 512) + 4);
        x[0]=v0.x; x[1]=v0.y; x[2]=v0.z; x[3]=v0.w;
        x[4]=v1.x; x[5]=v1.y; x[6]=v1.z; x[7]=v1.w;
    } else {
#pragma unroll
        for (int j = 0; j < 8; ++j) x[j] = 0.f;
    }
    unsigned short s0[8], s1[8], s2[8];
#pragma unroll
    for (int j = 0; j < 8; ++j) split3(x[j], s0[j], s1[j], s2[j]);
    const int u = (k8 >> 3) & 7;
    const int base = (k8 & ~63) + (((u ^ (m & 7))) << 3);
#pragma unroll
    for (int p = 0; p < 6; ++p) {
        ushort8v v;
#pragma unroll
        for (int j = 0; j < 8; ++j)
            v[j] = (c_ipt[p] == 0) ? s0[j] : ((c_ipt[p] == 1) ? s1[j] : s2[j]);
        *(ushort8v*)&g_Xb[m][p * 640 + base] = v;
    }
}

__global__ __launch_bounds__(256) void build_Wb(const float* __restrict__ Wk)
{
    const int tid = threadIdx.x;
    const int np = blockIdx.x * 16 + (tid >> 4);
    const int k8 = (blockIdx.y * 16 + (tid & 15)) * 8;
    const int n = (np & 3) * 512 + (np >> 2);
    float x[8];
#pragma unroll
    for (int j = 0; j < 8; ++j) x[j] = Wk[(size_t)(k8 + j) * 2048 + n];
    unsigned short s0[8], s1[8], s2[8];
#pragma unroll
    for (int j = 0; j < 8; ++j) split3(x[j], s0[j], s1[j], s2[j]);
    const int u = (k8 >> 3) & 7;
    const int base = (k8 & ~63) + (((u ^ (np & 7))) << 3);
#pragma unroll
    for (int p = 0; p < 6; ++p) {
        ushort8v v;
#pragma unroll
        for (int j = 0; j < 8; ++j)
            v[j] = (c_jpt[p] == 0) ? s0[j] : ((c_jpt[p] == 1) ? s1[j] : s2[j]);
        *(ushort8v*)&g_Wb[np][p * 640 + base] = v;
    }
}

__global__ __launch_bounds__(256) void build_Rb(const float* __restrict__ Rk)
{
    const int tid = threadIdx.x;
    const int np = blockIdx.x * 16 + (tid >> 4);
    const int k8 = (blockIdx.y * 16 + (tid & 15)) * 8;
    const int n = (np & 3) * 512 + (np >> 2);
    float x[8];
#pragma unroll
    for (int j = 0; j < 8; ++j) x[j] = Rk[(size_t)(k8 + j) * 2048 + n];
    unsigned short s0[8], s1[8], s2[8];
#pragma unroll
    for (int j = 0; j < 8; ++j) split3(x[j], s0[j], s1[j], s2[j]);
    const int u = (k8 >> 3) & 7;
    const int base = (k8 & ~63) + (((u ^ (np & 7))) << 3);
    ushort8v v0, v1, v2;
#pragma unroll
    for (int j = 0; j < 8; ++j) { v0[j] = s0[j]; v1[j] = s1[j]; v2[j] = s2[j]; }
    *(ushort8v*)&g_Rb[np][0 * 512 + base] = v0;
    *(ushort8v*)&g_Rb[np][1 * 512 + base] = v1;
    *(ushort8v*)&g_Rb[np][2 * 512 + base] = v2;
}

__global__ __launch_bounds__(256) void build_misc(const float* __restrict__ sw,
                                                  const float* __restrict__ bias)
{
    int id = blockIdx.x * 256 + threadIdx.x;
    if (id < 128 * 512) {
        int c = id >> 9, r = id & 511;
        g_swT[c][r] = sw[(size_t)r * 128 + c];
    } else if (id < 128 * 512 + 2048) {
        int np = id - 128 * 512;
        g_bperm[np] = bias[(np & 3) * 512 + (np >> 2)];
    }
}

// ---------------- PRE = x@K + bias (MFMA, counted-vmcnt ring) ----------------
__global__ __launch_bounds__(256, 1) void pre_mfma()
{
    __shared__ __align__(16) char smem[98304];     // 4 slots x 24 KB
    const int tid = threadIdx.x, lane = tid & 63, wave = tid >> 6;
    const int n0 = blockIdx.x * 64, m0 = blockIdx.y * 128;
    const int wr = wave >> 1, wc = wave & 1, l15 = lane & 15, ql = lane >> 4;
    unsigned short* ring = (unsigned short*)smem;
    const unsigned short* Ag = &g_Xb[m0][0];
    const unsigned short* Bg = &g_Wb[n0][0];

    f32x4 acc[4][2];
#pragma unroll
    for (int a = 0; a < 4; ++a)
#pragma unroll
        for (int b = 0; b < 2; ++b) acc[a][b] = (f32x4){0.f, 0.f, 0.f, 0.f};

    stage_chunk<1024, 512>(Ag, KP_PRE, Bg, KP_PRE, 0, ring + 0 * 12288, tid);
    stage_chunk<1024, 512>(Ag, KP_PRE, Bg, KP_PRE, 1, ring + 1 * 12288, tid);
    stage_chunk<1024, 512>(Ag, KP_PRE, Bg, KP_PRE, 2, ring + 2 * 12288, tid);
    for (int c = 0; c < 60; ++c) {
        if (c <= 57)      WAITV(12);
        else if (c == 58) WAITV(6);
        else              WAITV(0);
        SBAR();
        const unsigned short* Ac = ring + (c & 3) * 12288;
        const unsigned short* Bc = Ac + 8192;
#pragma unroll
        for (int sub = 0; sub < 2; ++sub) {
            const int uw = sub * 4 + ql;
            short8v af[4], bfr[2];
#pragma unroll
            for (int fa = 0; fa < 4; ++fa)
                af[fa] = fragld(Ac, wr * 64 + fa * 16 + l15, uw);
#pragma unroll
            for (int fb = 0; fb < 2; ++fb)
                bfr[fb] = fragld(Bc, wc * 32 + fb * 16 + l15, uw);
#pragma unroll
            for (int fa = 0; fa < 4; ++fa)
#pragma unroll
                for (int fb = 0; fb < 2; ++fb)
                    acc[fa][fb] = __builtin_amdgcn_mfma_f32_16x16x32_bf16(
                        af[fa], bfr[fb], acc[fa][fb], 0, 0, 0);
        }
        if (c + 3 < 60)
            stage_chunk<1024, 512>(Ag, KP_PRE, Bg, KP_PRE, c + 3,
                                   ring + ((c + 3) & 3) * 12288, tid);
    }
#pragma unroll
    for (int fa = 0; fa < 4; ++fa)
#pragma unroll
        for (int fb = 0; fb < 2; ++fb) {
            const int np = n0 + wc * 32 + fb * 16 + l15;
            const float bv = g_bperm[np];
#pragma unroll
            for (int q = 0; q < 4; ++q) {
                const int m = m0 + wr * 64 + fa * 16 + ql * 4 + q;
                g_pre[m][np] = acc[fa][fb][q] + bv;
            }
        }
}

// ---------------- persistent recurrence (512 threads, pair map, nt stores) ---
__global__ __launch_bounds__(512, 1) void charnn_rec(
    const float* __restrict__ sb,
    float* __restrict__ seq, float* __restrict__ out_h, float* __restrict__ out_c)
{
    __shared__ __align__(16) char smem[147456];    // 3 ring bufs x 48 KB; zbuf alias
    float (*zbuf)[68] = (float (*)[68])smem;       // 17 KB, inside slot0 A-half
    unsigned short* ring = (unsigned short*)smem;

    const int bi = blockIdx.x, tid = threadIdx.x;
    const int lane = tid & 63, wave = tid >> 6;    // wave 0..7
    // XCD-PAIR map (R3/R6): XCD x = 2P+e hosts Mg in {2P,2P+1} x 16 Ng.
    // B (g_Rb panels, 3.07 MB/XCD) is L2-RESIDENT -> low miss bytes.
    // h handoff (g_hs/g_hf/g_plv) is nt-STORED: lines stream past L2 to MALL,
    // so partner-XCD readers fetch CLEAN at stream rate (no dirty-probe tax).
    // Leader wbl2 per XCD (R6) kept as correctness backstop if nt lands dirty.
    const int x  = bi & 7, jj = bi >> 3;
    const int P  = x >> 1, e = x & 1;
    const int Mg = 2 * P + (jj & 1);                 // 0..7
    const int Ng = e * 16 + (jj >> 1);               // 0..31
    const int m0 = Mg * 64, n0 = Ng * 64;
    // z-tile wave split 2x4 (R8): 32 rows x 16 cols per wave
    const int wr = wave >> 2, wc = wave & 3, l15 = lane & 15, ql = lane >> 4;

    // epilogue ownership: 2 cells (one m-row, 2 consecutive r-locals)
    const int m_e = tid >> 3;            // 0..63
    const int rb2 = (tid & 7) * 2;       // 0,2,..,14
    const int mg = m0 + m_e;
    float cst[2] = {0.f, 0.f};

    // logits/argmax mapping aligned to pair rows (R6, all dataflow pair-local)
    const int q    = e * 32 + jj;        // 0..63 within pair
    const int rgrp = 8 * P + (q & 7);
    const int cg   = q >> 3;
    const int arow = 128 * P + q * 2;
    const bool xleader = (jj == 0);
    const bool pleader = (jj == 0 && e == 0);

    constexpr int ipt[6] = {0, 0, 1, 0, 1, 2};
    constexpr int jpt[6] = {0, 1, 0, 2, 1, 0};

    const unsigned short* Bg = &g_Rb[n0][0];

    // prologue: pre row for t=0 (cold HBM)
    f32x4 pqa, pqb;
    {
        const float* prow = &g_pre[0 * 512 + mg][n0];
        pqa = *(const f32x4*)(prow + rb2 * 4);
        pqb = *(const f32x4*)(prow + rb2 * 4 + 4);
    }

    for (int ph = 0; ph < 34; ++ph) {
        const int t = ph;
        const bool do_z = (ph >= 1 && ph <= 31);

        // ---- A-only prologue staging (kr0-2); latency hides under logits ----
        const unsigned short* Ag = nullptr;
        if (do_z) {
            Ag = &g_hs[(t + 1) & 1][m0][0];
            stageA3w(Ag, 0, ring + 0 * 24576, tid);
            stageA3w(Ag, 1, ring + 1 * 24576, tid);
            stageA3w(Ag, 2, ring + 2 * 24576, tid);
        }

        // ---- logits partials for t = ph-1: tid<256, EXACT proven code ----
        if (ph >= 1 && ph <= 32 && tid < 256) {
            const int tl = ph - 1;
            const int row = rgrp * 16 + (tid >> 4);
            const int col = cg * 16 + (tid & 15);
            const float* hrow = &g_hf[tl & 1][(size_t)row * 512];
            const float* wcol = &g_swT[col][0];
            float s0 = sb[col], s1 = 0.f, s2 = 0.f, s3 = 0.f;
#pragma unroll 8
            for (int k = 0; k < 512; k += 4) {
                float4 hv = *(const float4*)(hrow + k);
                float4 wv = *(const float4*)(wcol + k);
                s0 = fmaf(hv.x, wv.x, s0); s1 = fmaf(hv.y, wv.y, s1);
                s2 = fmaf(hv.z, wv.z, s2); s3 = fmaf(hv.w, wv.w, s3);
            }
            float bv = (s0 + s1) + (s2 + s3); int bidx = col;
#pragma unroll
            for (int m = 1; m < 16; m <<= 1) {
                float ov = __shfl_xor(bv, m, 64);
                int   oi = __shfl_xor(bidx, m, 64);
                if (ov > bv || (ov == bv && oi < bidx)) { bv = ov; bidx = oi; }
            }
            if ((tid & 15) == 0) {
                __builtin_nontemporal_store(bv,   &g_plv[tl & 1][row * 8 + cg]);
                __builtin_nontemporal_store(bidx, &g_pli[tl & 1][row * 8 + cg]);
            }
        }

        // ---- finalize argmax for t = ph-2 -> one-hot (2 rows/block) ----
        if (ph >= 2 && wave < 2) {
            const int t2 = ph - 2;
            const int row = arow + wave;
            float v; int idx;
            if (lane < 8) {
                v   = g_plv[t2 & 1][row * 8 + lane];
                idx = g_pli[t2 & 1][row * 8 + lane];
            } else { v = -INFINITY; idx = 0x7fffffff; }
#pragma unroll
            for (int m = 1; m < 8; m <<= 1) {
                float ov = __shfl_xor(v, m, 64);
                int   oi = __shfl_xor(idx, m, 64);
                if (ov > v || (ov == v && oi < idx)) { v = ov; idx = oi; }
            }
            int win = __shfl(idx, 0, 64);
            if (lane < 32) {
                int c4 = lane * 4;
                float4 o;
                o.x = (c4 + 0 == win) ? 1.f : 0.f;
                o.y = (c4 + 1 == win) ? 1.f : 0.f;
                o.z = (c4 + 2 == win) ? 1.f : 0.f;
                o.w = (c4 + 3 == win) ? 1.f : 0.f;
                *(float4*)(seq + ((size_t)row * 32 + t2) * 128 + c4) = o;
            }
        }

        // ---- z-MFMA (counted-vmcnt ring, 8 waves 2x4, R8) + gates ----
        if (ph <= 31) {
            if (do_z) {
                f32x4 acc[2];
                acc[0] = (f32x4){0.f, 0.f, 0.f, 0.f};
                acc[1] = (f32x4){0.f, 0.f, 0.f, 0.f};
#pragma unroll
                for (int kr = 0; kr < 8; ++kr) {
                    if (kr >= 1 && kr <= 5)
                        stage6w(Ag, Bg, kr + 2, ring + ((kr + 2) % 3) * 24576, tid);
                    if      (kr == 0) WAITV(6);
                    else if (kr == 1) WAITV(9);
                    else if (kr == 6) WAITV(6);
                    else if (kr == 7) WAITV(0);
                    else              WAITV(12);
                    SBAR();
                    const unsigned short* Ab = ring + (kr % 3) * 24576;
                    const unsigned short* Bb = Ab + 12288;
#pragma unroll
                    for (int sub = 0; sub < 2; ++sub) {
                        const int uw = sub * 4 + ql;
                        short8v a0[2], a1[2], a2[2], b0, b1, b2;
                        a0[0] = fragld(Ab + 0 * 4096, wr * 32 + l15, uw);
                        a0[1] = fragld(Ab + 0 * 4096, wr * 32 + 16 + l15, uw);
                        a1[0] = fragld(Ab + 1 * 4096, wr * 32 + l15, uw);
                        a1[1] = fragld(Ab + 1 * 4096, wr * 32 + 16 + l15, uw);
                        a2[0] = fragld(Ab + 2 * 4096, wr * 32 + l15, uw);
                        a2[1] = fragld(Ab + 2 * 4096, wr * 32 + 16 + l15, uw);
                        b0 = fragld(Bb + 0 * 4096, wc * 16 + l15, uw);
                        b1 = fragld(Bb + 1 * 4096, wc * 16 + l15, uw);
                        b2 = fragld(Bb + 2 * 4096, wc * 16 + l15, uw);
#pragma unroll
                        for (int p = 0; p < 6; ++p) {
                            const short8v* A2 = (ipt[p] == 0) ? a0 :
                                                ((ipt[p] == 1) ? a1 : a2);
                            const short8v  B2 = (jpt[p] == 0) ? b0 :
                                                ((jpt[p] == 1) ? b1 : b2);
                            acc[0] = __builtin_amdgcn_mfma_f32_16x16x32_bf16(
                                A2[0], B2, acc[0], 0, 0, 0);
                            acc[1] = __builtin_amdgcn_mfma_f32_16x16x32_bf16(
                                A2[1], B2, acc[1], 0, 0, 0);
                        }
                    }
                }
                __syncthreads();   // drain ring reads; ring -> zbuf reuse safe
#pragma unroll
                for (int fa = 0; fa < 2; ++fa)
#pragma unroll
                    for (int q2 = 0; q2 < 4; ++q2)
                        zbuf[wr * 32 + fa * 16 + ql * 4 + q2]
                            [wc * 16 + l15] = acc[fa][q2];
            }
            __syncthreads();

            unsigned short hs0[2], hs1[2], hs2[2];
            float hv2[2];
#pragma unroll
            for (int i = 0; i < 2; ++i) {
                const int rl = rb2 + i;
                float zi, zf, zg, zo;
                if (t > 0) {
                    float4 zq = *(const float4*)&zbuf[m_e][rl * 4];
                    zi = zq.x; zf = zq.y; zg = zq.z; zo = zq.w;
                } else { zi = zf = zg = zo = 0.f; }
                f32x4 pq = (i == 0) ? pqa : pqb;
                zi += pq[0]; zf += pq[1]; zg += pq[2]; zo += pq[3];
                float c2 = sigf(zf) * cst[i] + sigf(zi) * tanhf(zg);
                float h2 = sigf(zo) * tanhf(c2);
                cst[i] = c2;
                hv2[i] = h2;
                split3(h2, hs0[i], hs1[i], hs2[i]);
            }
            const int r0g = Ng * 16 + rb2;
            {
                f32x2 hv = {hv2[0], hv2[1]};
                __builtin_nontemporal_store(
                    hv, (f32x2*)&g_hf[t & 1][(size_t)mg * 512 + r0g]);
            }
            if (t == 31) {
                *(float2*)&out_h[(size_t)mg * 512 + r0g] =
                    make_float2(hv2[0], hv2[1]);
                *(float2*)&out_c[(size_t)mg * 512 + r0g] =
                    make_float2(cst[0], cst[1]);
            }
            // h splits -> g_hs (nt): 3 splits, 2 consecutive k' = one 4B store
            const int su = ((r0g >> 3) & 7) ^ (mg & 7);
            const int abase = (r0g & ~63) + (su << 3) + (r0g & 7);
#pragma unroll
            for (int i = 0; i < 3; ++i) {
                ushort2v v;
#pragma unroll
                for (int j = 0; j < 2; ++j)
                    v[j] = (i == 0) ? hs0[j] : ((i == 1) ? hs1[j] : hs2[j]);
                __builtin_nontemporal_store(
                    v, (ushort2v*)&g_hs[t & 1][mg][i * 512 + abase]);
            }
        }

        // ---- 3-level barrier (R6): per-XCD arrival -> leader wbl2 -> pair ---
        if (ph < 33) {
            __syncthreads();   // drains all stores (incl. nt) via vmcnt0

            // cross-barrier prefetch: B kr0-2 into ring B-halves + next pre row
            if (ph <= 30) {
                stageB3w(Bg, 0, ring + 0 * 24576, tid);
                stageB3w(Bg, 1, ring + 1 * 24576, tid);
                stageB3w(Bg, 2, ring + 2 * 24576, tid);
                const float* prow = &g_pre[(ph + 1) * 512 + mg][n0];
                pqa = *(const f32x4*)(prow + rb2 * 4);
                pqb = *(const f32x4*)(prow + rb2 * 4 + 4);
            }

            if (tid == 0) {
                __hip_atomic_fetch_add(&g_xcnt[x * 16], 1u,
                                       __ATOMIC_RELAXED, __HIP_MEMORY_SCOPE_AGENT);
                if (xleader) {
                    const unsigned xt = 32u * (unsigned)(ph + 1);
                    while (__hip_atomic_load(&g_xcnt[x * 16], __ATOMIC_RELAXED,
                                             __HIP_MEMORY_SCOPE_AGENT) < xt)
                        __builtin_amdgcn_s_sleep(2);
                    // ONE release fence per XCD: flushes any dirty handoff
                    // lines (nt stores should leave few) before pair release.
                    __builtin_amdgcn_fence(__ATOMIC_RELEASE, "agent");
                    __hip_atomic_fetch_add(&g_pcnt[P * 64], 1u,
                                           __ATOMIC_RELAXED, __HIP_MEMORY_SCOPE_AGENT);
                    if (pleader) {
                        const unsigned pt = 2u * (unsigned)(ph + 1);
                        while (__hip_atomic_load(&g_pcnt[P * 64], __ATOMIC_RELAXED,
                                                 __HIP_MEMORY_SCOPE_AGENT) < pt)
                            __builtin_amdgcn_s_sleep(2);
                        __hip_atomic_store(&g_prel[P * 64], (unsigned)(ph + 1),
                                           __ATOMIC_RELAXED, __HIP_MEMORY_SCOPE_AGENT);
                    }
                }
                while (__hip_atomic_load(&g_prel[P * 64], __ATOMIC_RELAXED,
                                         __HIP_MEMORY_SCOPE_AGENT) < (unsigned)(ph + 1))
                    __builtin_amdgcn_s_sleep(2);
                __builtin_amdgcn_fence(__ATOMIC_ACQUIRE, "agent");
            }
            __syncthreads();
        }
    }
}

// ---------------------------------------------------------------------------
extern "C" void kernel_launch(void* const* d_in, const int* in_sizes, int n_in,
                              void* d_out, int out_size, void* d_ws, size_t ws_size,
                              hipStream_t stream)
{
    const float* fp   = (const float*)d_in[0];  // f_pool       [512,32,512]
    const float* gt   = (const float*)d_in[1];  // ground_truth [512,32,128]
    const float* Wk   = (const float*)d_in[2];  // kernel       [640,2048]
    const float* Rk   = (const float*)d_in[3];  // rec_kernel   [512,2048]
    const float* bias = (const float*)d_in[4];  // [2048]
    const float* sw   = (const float*)d_in[5];  // softmax_w    [512,128]
    const float* sb   = (const float*)d_in[6];  // softmax_b    [128]
    float* seq   = (float*)d_out;                        // [512,32,128]
    float* out_h = seq + (size_t)512 * 32 * 128;         // [512,512]
    float* out_c = out_h + (size_t)512 * 512;            // [512,512]

    hipLaunchKernelGGL(init_counters, dim3(1), dim3(64), 0, stream);
    hipLaunchKernelGGL(build_Xb, dim3(1024, 5), dim3(256), 0, stream, fp, gt);
    hipLaunchKernelGGL(build_Wb, dim3(128, 5), dim3(256), 0, stream, Wk);
    hipLaunchKernelGGL(build_Rb, dim3(128, 4), dim3(256), 0, stream, Rk);
    hipLaunchKernelGGL(build_misc, dim3(264), dim3(256), 0, stream, sw, bias);
    hipLaunchKernelGGL(pre_mfma, dim3(32, 128), dim3(256), 0, stream);
    hipLaunchKernelGGL(charnn_rec, dim3(256), dim3(512), 0, stream,
                       sb, seq, out_h, out_c);
}

// Round 11
// 1458.428 us; speedup vs baseline: 1.1640x; 1.1640x over previous
//
#include <hip/hip_runtime.h>
#include <math.h>

typedef float  f32x4  __attribute__((ext_vector_type(4)));
typedef short  short8v __attribute__((ext_vector_type(8)));
typedef unsigned short ushort8v __attribute__((ext_vector_type(8)));
typedef unsigned short ushort2v __attribute__((ext_vector_type(2)));

#define KP_PRE 1920
#define KP_HS  1536

#define WAITV(N) asm volatile("s_waitcnt vmcnt(" #N ")" ::: "memory")
#define SBAR()   asm volatile("s_barrier" ::: "memory")

// ---------------- persistent device state ----------------------------------
__device__ unsigned short g_Xb[16384][1920];  // pre A (x 3 i-splits, swizzled)
__device__ unsigned short g_Wb[2048][1920];   // pre B^T (kernel 3 j-splits)
__device__ unsigned short g_Rb[2048][1536];   // z   B^T (rec_kernel, 3 j-splits)
__device__ unsigned short g_hs[2][512][1536]; // h 3 i-splits, ping-pong
__device__ float g_pre[16384][2048];          // x@K + bias (gate-interleaved)
__device__ float g_hf[2][512 * 512];          // h f32, ping-pong
__device__ float g_swT[128][512];             // softmax_w transposed
__device__ float g_bperm[2048];               // bias, gate-interleaved cols
__device__ float g_plv[2][512 * 8];
__device__ int   g_pli[2][512 * 8];
__device__ unsigned g_xcnt[128];              // 8 per-XCD arrival counters
__device__ unsigned g_xrel[128];              // 8 per-XCD release flags

__global__ void init_counters()
{
    int t = threadIdx.x;
    if (t < 8) { g_xcnt[t * 16] = 0u; g_xrel[t * 16] = 0u; }
}

// ---------------- helpers ---------------------------------------------------
__device__ __forceinline__ unsigned short f2bf(float f) {
    unsigned u = __float_as_uint(f);
    return (unsigned short)((u + 0x7fffu + ((u >> 16) & 1u)) >> 16);
}
__device__ __forceinline__ float bf2f(unsigned short s) {
    return __uint_as_float(((unsigned)s) << 16);
}
__device__ __forceinline__ float sigf(float x) { return 1.f / (1.f + expf(-x)); }

__device__ __forceinline__ void split3(float v, unsigned short& s0,
                                       unsigned short& s1, unsigned short& s2) {
    s0 = f2bf(v); float f0 = bf2f(s0);
    s1 = f2bf(v - f0); float f1 = bf2f(s1);
    s2 = f2bf(v - f0 - f1);
}

__device__ __forceinline__ void gl16(const unsigned short* g, unsigned short* l) {
    __builtin_amdgcn_global_load_lds((const __attribute__((address_space(1))) void*)g,
                                     (__attribute__((address_space(3))) void*)l, 16, 0, 0);
}

// LDS tile: [rows][64] bf16, row = 128B, 16B-units XOR-swizzled by (row&7)
__device__ __forceinline__ short8v fragld(const unsigned short* sh, int row, int uw) {
    return *(const short8v*)(sh + row * 64 + ((uw ^ (row & 7)) << 3));
}

// pre staging: one kr chunk (64 K-elems) = A 3 splits (128 rows) + B 3 (64)
__device__ __forceinline__ void stage_pre(const unsigned short* Ag,
                                          const unsigned short* Bg,
                                          int kr, unsigned short* slot, int tid)
{
#pragma unroll
    for (int s = 0; s < 3; ++s)
#pragma unroll
        for (int v = 0; v < 4; ++v) {
            int e = v * 256 + tid;
            gl16(Ag + (size_t)(e >> 3) * KP_PRE + s * 640 + kr * 64 + (e & 7) * 8,
                 slot + s * 8192 + e * 8);
        }
#pragma unroll
    for (int s = 0; s < 3; ++s)
#pragma unroll
        for (int v = 0; v < 2; ++v) {
            int e = v * 256 + tid;
            gl16(Bg + (size_t)(e >> 3) * KP_PRE + s * 640 + kr * 64 + (e & 7) * 8,
                 slot + 24576 + s * 4096 + e * 8);
        }
}

// z-path staging, 512-thread variant: one gl16 per split per thread
__device__ __forceinline__ void stageA3w(const unsigned short* Ag, int kr,
                                         unsigned short* buf, int tid)
{
#pragma unroll
    for (int s = 0; s < 3; ++s) {
        int e = tid;   // 0..511 = 64 rows x 8 units
        gl16(Ag + (size_t)(e >> 3) * KP_HS + (s * 8 + kr) * 64 + (e & 7) * 8,
             buf + s * 4096 + e * 8);
    }
}
__device__ __forceinline__ void stageB3w(const unsigned short* Bg, int kr,
                                         unsigned short* buf, int tid)
{
#pragma unroll
    for (int s = 0; s < 3; ++s) {
        int e = tid;
        gl16(Bg + (size_t)(e >> 3) * KP_HS + (s * 8 + kr) * 64 + (e & 7) * 8,
             buf + 12288 + s * 4096 + e * 8);
    }
}
__device__ __forceinline__ void stage6w(const unsigned short* Ag,
                                        const unsigned short* Bg,
                                        int kr, unsigned short* buf, int tid)
{
    stageA3w(Ag, kr, buf, tid);
    stageB3w(Bg, kr, buf, tid);
}

// ---------------- builders --------------------------------------------------
__global__ __launch_bounds__(256) void build_Xb(const float* __restrict__ fp,
                                                const float* __restrict__ gt)
{
    const int tid = threadIdx.x;
    const int m  = blockIdx.x * 16 + (tid >> 4);
    const int k8 = (blockIdx.y * 16 + (tid & 15)) * 8;
    const int t = m >> 9, b = m & 511;
    float x[8];
    if (k8 < 512) {
        float4 v0 = *(const float4*)(fp + ((size_t)(b * 32 + t)) * 512 + k8);
        float4 v1 = *(const float4*)(fp + ((size_t)(b * 32 + t)) * 512 + k8 + 4);
        x[0]=v0.x; x[1]=v0.y; x[2]=v0.z; x[3]=v0.w;
        x[4]=v1.x; x[5]=v1.y; x[6]=v1.z; x[7]=v1.w;
    } else if (t > 0) {
        float4 v0 = *(const float4*)(gt + ((size_t)(b * 32 + t - 1)) * 128 + (k8 - 512));
        float4 v1 = *(const float4*)(gt + ((size_t)(b * 32 + t - 1)) * 128 + (k8 - 512) + 4);
        x[0]=v0.x; x[1]=v0.y; x[2]=v0.z; x[3]=v0.w;
        x[4]=v1.x; x[5]=v1.y; x[6]=v1.z; x[7]=v1.w;
    } else {
#pragma unroll
        for (int j = 0; j < 8; ++j) x[j] = 0.f;
    }
    unsigned short s0[8], s1[8], s2[8];
#pragma unroll
    for (int j = 0; j < 8; ++j) split3(x[j], s0[j], s1[j], s2[j]);
    const int u = (k8 >> 3) & 7;
    const int base = (k8 & ~63) + (((u ^ (m & 7))) << 3);
    ushort8v v0, v1, v2;
#pragma unroll
    for (int j = 0; j < 8; ++j) { v0[j] = s0[j]; v1[j] = s1[j]; v2[j] = s2[j]; }
    *(ushort8v*)&g_Xb[m][0 * 640 + base] = v0;
    *(ushort8v*)&g_Xb[m][1 * 640 + base] = v1;
    *(ushort8v*)&g_Xb[m][2 * 640 + base] = v2;
}

__global__ __launch_bounds__(256) void build_Wb(const float* __restrict__ Wk)
{
    const int tid = threadIdx.x;
    const int np = blockIdx.x * 16 + (tid >> 4);
    const int k8 = (blockIdx.y * 16 + (tid & 15)) * 8;
    const int n = (np & 3) * 512 + (np >> 2);
    float x[8];
#pragma unroll
    for (int j = 0; j < 8; ++j) x[j] = Wk[(size_t)(k8 + j) * 2048 + n];
    unsigned short s0[8], s1[8], s2[8];
#pragma unroll
    for (int j = 0; j < 8; ++j) split3(x[j], s0[j], s1[j], s2[j]);
    const int u = (k8 >> 3) & 7;
    const int base = (k8 & ~63) + (((u ^ (np & 7))) << 3);
    ushort8v v0, v1, v2;
#pragma unroll
    for (int j = 0; j < 8; ++j) { v0[j] = s0[j]; v1[j] = s1[j]; v2[j] = s2[j]; }
    *(ushort8v*)&g_Wb[np][0 * 640 + base] = v0;
    *(ushort8v*)&g_Wb[np][1 * 640 + base] = v1;
    *(ushort8v*)&g_Wb[np][2 * 640 + base] = v2;
}

__global__ __launch_bounds__(256) void build_Rb(const float* __restrict__ Rk)
{
    const int tid = threadIdx.x;
    const int np = blockIdx.x * 16 + (tid >> 4);
    const int k8 = (blockIdx.y * 16 + (tid & 15)) * 8;
    const int n = (np & 3) * 512 + (np >> 2);
    float x[8];
#pragma unroll
    for (int j = 0; j < 8; ++j) x[j] = Rk[(size_t)(k8 + j) * 2048 + n];
    unsigned short s0[8], s1[8], s2[8];
#pragma unroll
    for (int j = 0; j < 8; ++j) split3(x[j], s0[j], s1[j], s2[j]);
    const int u = (k8 >> 3) & 7;
    const int base = (k8 & ~63) + (((u ^ (np & 7))) << 3);
    ushort8v v0, v1, v2;
#pragma unroll
    for (int j = 0; j < 8; ++j) { v0[j] = s0[j]; v1[j] = s1[j]; v2[j] = s2[j]; }
    *(ushort8v*)&g_Rb[np][0 * 512 + base] = v0;
    *(ushort8v*)&g_Rb[np][1 * 512 + base] = v1;
    *(ushort8v*)&g_Rb[np][2 * 512 + base] = v2;
}

__global__ __launch_bounds__(256) void build_misc(const float* __restrict__ sw,
                                                  const float* __restrict__ bias)
{
    int id = blockIdx.x * 256 + threadIdx.x;
    if (id < 128 * 512) {
        int c = id >> 9, r = id & 511;
        g_swT[c][r] = sw[(size_t)r * 128 + c];
    } else if (id < 128 * 512 + 2048) {
        int np = id - 128 * 512;
        g_bperm[np] = bias[(np & 3) * 512 + (np >> 2)];
    }
}

// ---------------- PRE = x@K + bias (compact 3-split, 2-deep 72KB ring) -------
__global__ __launch_bounds__(256, 1) void pre_mfma()
{
    __shared__ __align__(16) char smem[147456];    // 2 slots x 72 KB
    const int tid = threadIdx.x, lane = tid & 63, wave = tid >> 6;
    // XCD swizzle: all 32 n-blocks of one m-row land on ONE XCD -> each
    // A-panel (492 KB compact) is fetched from HBM once, not once per XCD.
    // B (7.9 MB compact) stays L3-hot.
    const int vid = blockIdx.y * 32 + blockIdx.x;   // dispatch-linear id
    const int x8 = vid & 7, k = vid >> 3;           // XCD, index within XCD
    const int m0 = (x8 + 8 * (k >> 5)) * 128;       // 16 m-rows per XCD
    const int n0 = (k & 31) * 64;
    const int wr = wave >> 1, wc = wave & 1, l15 = lane & 15, ql = lane >> 4;
    unsigned short* ring = (unsigned short*)smem;
    const unsigned short* Ag = &g_Xb[m0][0];
    const unsigned short* Bg = &g_Wb[n0][0];

    constexpr int ipt[6] = {0, 0, 1, 0, 1, 2};
    constexpr int jpt[6] = {0, 1, 0, 2, 1, 0};

    f32x4 acc[4][2];
#pragma unroll
    for (int a = 0; a < 4; ++a)
#pragma unroll
        for (int b = 0; b < 2; ++b) acc[a][b] = (f32x4){0.f, 0.f, 0.f, 0.f};

    stage_pre(Ag, Bg, 0, ring, tid);
    stage_pre(Ag, Bg, 1, ring + 36864, tid);
    for (int kr = 0; kr < 10; ++kr) {
        if (kr <= 8) WAITV(18);      // next chunk's 18 loads may stay in flight
        else         WAITV(0);
        SBAR();
        const unsigned short* Ab = ring + (kr & 1) * 36864;
        const unsigned short* Bb = Ab + 24576;
#pragma unroll
        for (int sub = 0; sub < 2; ++sub) {
            const int uw = sub * 4 + ql;
            short8v a0[4], a1[4], a2[4], b0[2], b1[2], b2[2];
#pragma unroll
            for (int fa = 0; fa < 4; ++fa) {
                a0[fa] = fragld(Ab + 0 * 8192, wr * 64 + fa * 16 + l15, uw);
                a1[fa] = fragld(Ab + 1 * 8192, wr * 64 + fa * 16 + l15, uw);
                a2[fa] = fragld(Ab + 2 * 8192, wr * 64 + fa * 16 + l15, uw);
            }
#pragma unroll
            for (int fb = 0; fb < 2; ++fb) {
                b0[fb] = fragld(Bb + 0 * 4096, wc * 32 + fb * 16 + l15, uw);
                b1[fb] = fragld(Bb + 1 * 4096, wc * 32 + fb * 16 + l15, uw);
                b2[fb] = fragld(Bb + 2 * 4096, wc * 32 + fb * 16 + l15, uw);
            }
#pragma unroll
            for (int p = 0; p < 6; ++p) {
                const short8v* A2 = (ipt[p] == 0) ? a0 : ((ipt[p] == 1) ? a1 : a2);
                const short8v* B2 = (jpt[p] == 0) ? b0 : ((jpt[p] == 1) ? b1 : b2);
#pragma unroll
                for (int fa = 0; fa < 4; ++fa)
#pragma unroll
                    for (int fb = 0; fb < 2; ++fb)
                        acc[fa][fb] = __builtin_amdgcn_mfma_f32_16x16x32_bf16(
                            A2[fa], B2[fb], acc[fa][fb], 0, 0, 0);
            }
        }
        SBAR();   // all waves done reading slot before restaging it
        if (kr + 2 < 10)
            stage_pre(Ag, Bg, kr + 2, ring + (kr & 1) * 36864, tid);
    }
#pragma unroll
    for (int fa = 0; fa < 4; ++fa)
#pragma unroll
        for (int fb = 0; fb < 2; ++fb) {
            const int np = n0 + wc * 32 + fb * 16 + l15;
            const float bv = g_bperm[np];
#pragma unroll
            for (int q = 0; q < 4; ++q) {
                const int m = m0 + wr * 64 + fa * 16 + ql * 4 + q;
                g_pre[m][np] = acc[fa][fb][q] + bv;
            }
        }
}

// ---------------- persistent recurrence (R8 verbatim: XCD-local, 512t) -------
__global__ __launch_bounds__(512, 1) void charnn_rec(
    const float* __restrict__ sb,
    float* __restrict__ seq, float* __restrict__ out_h, float* __restrict__ out_c)
{
    __shared__ __align__(16) char smem[147456];    // 3 ring bufs x 48 KB; zbuf alias
    float (*zbuf)[68] = (float (*)[68])smem;       // 17 KB, inside slot0 A-half
    unsigned short* ring = (unsigned short*)smem;

    const int bi = blockIdx.x, tid = threadIdx.x;
    const int lane = tid & 63, wave = tid >> 6;    // wave 0..7
    const int x  = bi & 7, jj = bi >> 3;
    const int Mg = x;                                // == XCD id
    const int Ng = jj;                               // 0..31
    const int m0 = Mg * 64, n0 = Ng * 64;
    const int wr = wave >> 2, wc = wave & 3, l15 = lane & 15, ql = lane >> 4;

    const int m_e = tid >> 3;            // 0..63
    const int rb2 = (tid & 7) * 2;       // 0,2,..,14
    const int mg = m0 + m_e;
    float cst[2] = {0.f, 0.f};

    const int rgrp = Mg * 4 + (jj & 3);
    const int cg   = jj >> 2;
    const int arow = Mg * 64 + jj * 2;
    const bool xleader = (jj == 0);

    constexpr int ipt[6] = {0, 0, 1, 0, 1, 2};
    constexpr int jpt[6] = {0, 1, 0, 2, 1, 0};

    const unsigned short* Bg = &g_Rb[n0][0];

    f32x4 pqa, pqb;
    {
        const float* prow = &g_pre[0 * 512 + mg][n0];
        pqa = *(const f32x4*)(prow + rb2 * 4);
        pqb = *(const f32x4*)(prow + rb2 * 4 + 4);
    }

    for (int ph = 0; ph < 34; ++ph) {
        const int t = ph;
        const bool do_z = (ph >= 1 && ph <= 31);

        const unsigned short* Ag = nullptr;
        if (do_z) {
            Ag = &g_hs[(t + 1) & 1][m0][0];
            stageA3w(Ag, 0, ring + 0 * 24576, tid);
            stageA3w(Ag, 1, ring + 1 * 24576, tid);
            stageA3w(Ag, 2, ring + 2 * 24576, tid);
        }

        if (ph >= 1 && ph <= 32 && tid < 256) {
            const int tl = ph - 1;
            const int row = rgrp * 16 + (tid >> 4);
            const int col = cg * 16 + (tid & 15);
            const float* hrow = &g_hf[tl & 1][(size_t)row * 512];
            const float* wcol = &g_swT[col][0];
            float s0 = sb[col], s1 = 0.f, s2 = 0.f, s3 = 0.f;
#pragma unroll 8
            for (int k = 0; k < 512; k += 4) {
                float4 hv = *(const float4*)(hrow + k);
                float4 wv = *(const float4*)(wcol + k);
                s0 = fmaf(hv.x, wv.x, s0); s1 = fmaf(hv.y, wv.y, s1);
                s2 = fmaf(hv.z, wv.z, s2); s3 = fmaf(hv.w, wv.w, s3);
            }
            float bv = (s0 + s1) + (s2 + s3); int bidx = col;
#pragma unroll
            for (int m = 1; m < 16; m <<= 1) {
                float ov = __shfl_xor(bv, m, 64);
                int   oi = __shfl_xor(bidx, m, 64);
                if (ov > bv || (ov == bv && oi < bidx)) { bv = ov; bidx = oi; }
            }
            if ((tid & 15) == 0) {
                g_plv[tl & 1][row * 8 + cg] = bv;
                g_pli[tl & 1][row * 8 + cg] = bidx;
            }
        }

        if (ph >= 2 && wave < 2) {
            const int t2 = ph - 2;
            const int row = arow + wave;
            float v; int idx;
            if (lane < 8) {
                v   = g_plv[t2 & 1][row * 8 + lane];
                idx = g_pli[t2 & 1][row * 8 + lane];
            } else { v = -INFINITY; idx = 0x7fffffff; }
#pragma unroll
            for (int m = 1; m < 8; m <<= 1) {
                float ov = __shfl_xor(v, m, 64);
                int   oi = __shfl_xor(idx, m, 64);
                if (ov > v || (ov == v && oi < idx)) { v = ov; idx = oi; }
            }
            int win = __shfl(idx, 0, 64);
            if (lane < 32) {
                int c4 = lane * 4;
                float4 o;
                o.x = (c4 + 0 == win) ? 1.f : 0.f;
                o.y = (c4 + 1 == win) ? 1.f : 0.f;
                o.z = (c4 + 2 == win) ? 1.f : 0.f;
                o.w = (c4 + 3 == win) ? 1.f : 0.f;
                *(float4*)(seq + ((size_t)row * 32 + t2) * 128 + c4) = o;
            }
        }

        if (ph <= 31) {
            if (do_z) {
                f32x4 acc[2];
                acc[0] = (f32x4){0.f, 0.f, 0.f, 0.f};
                acc[1] = (f32x4){0.f, 0.f, 0.f, 0.f};
#pragma unroll
                for (int kr = 0; kr < 8; ++kr) {
                    if (kr >= 1 && kr <= 5)
                        stage6w(Ag, Bg, kr + 2, ring + ((kr + 2) % 3) * 24576, tid);
                    if      (kr == 0) WAITV(6);
                    else if (kr == 1) WAITV(9);
                    else if (kr == 6) WAITV(6);
                    else if (kr == 7) WAITV(0);
                    else              WAITV(12);
                    SBAR();
                    const unsigned short* Ab = ring + (kr % 3) * 24576;
                    const unsigned short* Bb = Ab + 12288;
#pragma unroll
                    for (int sub = 0; sub < 2; ++sub) {
                        const int uw = sub * 4 + ql;
                        short8v a0[2], a1[2], a2[2], b0, b1, b2;
                        a0[0] = fragld(Ab + 0 * 4096, wr * 32 + l15, uw);
                        a0[1] = fragld(Ab + 0 * 4096, wr * 32 + 16 + l15, uw);
                        a1[0] = fragld(Ab + 1 * 4096, wr * 32 + l15, uw);
                        a1[1] = fragld(Ab + 1 * 4096, wr * 32 + 16 + l15, uw);
                        a2[0] = fragld(Ab + 2 * 4096, wr * 32 + l15, uw);
                        a2[1] = fragld(Ab + 2 * 4096, wr * 32 + 16 + l15, uw);
                        b0 = fragld(Bb + 0 * 4096, wc * 16 + l15, uw);
                        b1 = fragld(Bb + 1 * 4096, wc * 16 + l15, uw);
                        b2 = fragld(Bb + 2 * 4096, wc * 16 + l15, uw);
#pragma unroll
                        for (int p = 0; p < 6; ++p) {
                            const short8v* A2 = (ipt[p] == 0) ? a0 :
                                                ((ipt[p] == 1) ? a1 : a2);
                            const short8v  B2 = (jpt[p] == 0) ? b0 :
                                                ((jpt[p] == 1) ? b1 : b2);
                            acc[0] = __builtin_amdgcn_mfma_f32_16x16x32_bf16(
                                A2[0], B2, acc[0], 0, 0, 0);
                            acc[1] = __builtin_amdgcn_mfma_f32_16x16x32_bf16(
                                A2[1], B2, acc[1], 0, 0, 0);
                        }
                    }
                }
                __syncthreads();   // drain ring reads; ring -> zbuf reuse safe
#pragma unroll
                for (int fa = 0; fa < 2; ++fa)
#pragma unroll
                    for (int q2 = 0; q2 < 4; ++q2)
                        zbuf[wr * 32 + fa * 16 + ql * 4 + q2]
                            [wc * 16 + l15] = acc[fa][q2];
            }
            __syncthreads();

            unsigned short hs0[2], hs1[2], hs2[2];
            float hv2[2];
#pragma unroll
            for (int i = 0; i < 2; ++i) {
                const int rl = rb2 + i;
                float zi, zf, zg, zo;
                if (t > 0) {
                    float4 zq = *(const float4*)&zbuf[m_e][rl * 4];
                    zi = zq.x; zf = zq.y; zg = zq.z; zo = zq.w;
                } else { zi = zf = zg = zo = 0.f; }
                f32x4 pq = (i == 0) ? pqa : pqb;
                zi += pq[0]; zf += pq[1]; zg += pq[2]; zo += pq[3];
                float c2 = sigf(zf) * cst[i] + sigf(zi) * tanhf(zg);
                float h2 = sigf(zo) * tanhf(c2);
                cst[i] = c2;
                hv2[i] = h2;
                split3(h2, hs0[i], hs1[i], hs2[i]);
            }
            const int r0g = Ng * 16 + rb2;
            *(float2*)&g_hf[t & 1][(size_t)mg * 512 + r0g] =
                make_float2(hv2[0], hv2[1]);
            if (t == 31) {
                *(float2*)&out_h[(size_t)mg * 512 + r0g] =
                    make_float2(hv2[0], hv2[1]);
                *(float2*)&out_c[(size_t)mg * 512 + r0g] =
                    make_float2(cst[0], cst[1]);
            }
            const int su = ((r0g >> 3) & 7) ^ (mg & 7);
            const int abase = (r0g & ~63) + (su << 3) + (r0g & 7);
#pragma unroll
            for (int i = 0; i < 3; ++i) {
                ushort2v v;
#pragma unroll
                for (int j = 0; j < 2; ++j)
                    v[j] = (i == 0) ? hs0[j] : ((i == 1) ? hs1[j] : hs2[j]);
                *(ushort2v*)&g_hs[t & 1][mg][i * 512 + abase] = v;
            }
        }

        if (ph < 33) {
            __syncthreads();

            if (ph <= 30) {
                stageB3w(Bg, 0, ring + 0 * 24576, tid);
                stageB3w(Bg, 1, ring + 1 * 24576, tid);
                stageB3w(Bg, 2, ring + 2 * 24576, tid);
                const float* prow = &g_pre[(ph + 1) * 512 + mg][n0];
                pqa = *(const f32x4*)(prow + rb2 * 4);
                pqb = *(const f32x4*)(prow + rb2 * 4 + 4);
            }

            if (tid == 0) {
                __hip_atomic_fetch_add(&g_xcnt[x * 16], 1u,
                                       __ATOMIC_RELAXED, __HIP_MEMORY_SCOPE_AGENT);
                if (xleader) {
                    const unsigned xt = 32u * (unsigned)(ph + 1);
                    while (__hip_atomic_load(&g_xcnt[x * 16], __ATOMIC_RELAXED,
                                             __HIP_MEMORY_SCOPE_AGENT) < xt)
                        __builtin_amdgcn_s_sleep(2);
                    __hip_atomic_store(&g_xrel[x * 16], (unsigned)(ph + 1),
                                       __ATOMIC_RELAXED, __HIP_MEMORY_SCOPE_AGENT);
                }
                while (__hip_atomic_load(&g_xrel[x * 16], __ATOMIC_RELAXED,
                                         __HIP_MEMORY_SCOPE_AGENT) < (unsigned)(ph + 1))
                    __builtin_amdgcn_s_sleep(2);
                __builtin_amdgcn_fence(__ATOMIC_ACQUIRE, "agent");
            }
            __syncthreads();
        }
    }
}

// ---------------------------------------------------------------------------
extern "C" void kernel_launch(void* const* d_in, const int* in_sizes, int n_in,
                              void* d_out, int out_size, void* d_ws, size_t ws_size,
                              hipStream_t stream)
{
    const float* fp   = (const float*)d_in[0];  // f_pool       [512,32,512]
    const float* gt   = (const float*)d_in[1];  // ground_truth [512,32,128]
    const float* Wk   = (const float*)d_in[2];  // kernel       [640,2048]
    const float* Rk   = (const float*)d_in[3];  // rec_kernel   [512,2048]
    const float* bias = (const float*)d_in[4];  // [2048]
    const float* sw   = (const float*)d_in[5];  // softmax_w    [512,128]
    const float* sb   = (const float*)d_in[6];  // softmax_b    [128]
    float* seq   = (float*)d_out;                        // [512,32,128]
    float* out_h = seq + (size_t)512 * 32 * 128;         // [512,512]
    float* out_c = out_h + (size_t)512 * 512;            // [512,512]

    hipLaunchKernelGGL(init_counters, dim3(1), dim3(64), 0, stream);
    hipLaunchKernelGGL(build_Xb, dim3(1024, 5), dim3(256), 0, stream, fp, gt);
    hipLaunchKernelGGL(build_Wb, dim3(128, 5), dim3(256), 0, stream, Wk);
    hipLaunchKernelGGL(build_Rb, dim3(128, 4), dim3(256), 0, stream, Rk);
    hipLaunchKernelGGL(build_misc, dim3(264), dim3(256), 0, stream, sw, bias);
    hipLaunchKernelGGL(pre_mfma, dim3(32, 128), dim3(256), 0, stream);
    hipLaunchKernelGGL(charnn_rec, dim3(256), dim3(512), 0, stream,
                       sb, seq, out_h, out_c);
}

// Round 12
// 1424.698 us; speedup vs baseline: 1.1916x; 1.0237x over previous
//
#include <hip/hip_runtime.h>
#include <math.h>

typedef float  f32x4  __attribute__((ext_vector_type(4)));
typedef short  short8v __attribute__((ext_vector_type(8)));
typedef unsigned short ushort8v __attribute__((ext_vector_type(8)));
typedef unsigned short ushort2v __attribute__((ext_vector_type(2)));

#define KP_PRE 1920
#define KP_HS  1536

#define WAITV(N) asm volatile("s_waitcnt vmcnt(" #N ")" ::: "memory")
#define SBAR()   asm volatile("s_barrier" ::: "memory")

// ---------------- persistent device state ----------------------------------
__device__ unsigned short g_Xb[16384][1920];  // pre A (x 3 i-splits, swizzled)
__device__ unsigned short g_Wb[2048][1920];   // pre B^T (kernel 3 j-splits)
__device__ unsigned short g_Rb[2048][1536];   // z   B^T (rec_kernel, 3 j-splits)
__device__ unsigned short g_hs[2][512][1536]; // h 3 i-splits, ping-pong
__device__ float g_pre[16384][2048];          // x@K + bias (gate-interleaved)
__device__ float g_hf[2][512 * 512];          // h f32, ping-pong
__device__ float g_swT[128][512];             // softmax_w transposed
__device__ float g_bperm[2048];               // bias, gate-interleaved cols
__device__ float g_plv[2][512 * 8];
__device__ int   g_pli[2][512 * 8];
__device__ unsigned g_xcnt[128];              // 8 per-XCD arrival counters
__device__ unsigned g_xrel[128];              // 8 per-XCD release flags

__global__ void init_counters()
{
    int t = threadIdx.x;
    if (t < 8) { g_xcnt[t * 16] = 0u; g_xrel[t * 16] = 0u; }
}

// ---------------- helpers ---------------------------------------------------
__device__ __forceinline__ unsigned short f2bf(float f) {
    unsigned u = __float_as_uint(f);
    return (unsigned short)((u + 0x7fffu + ((u >> 16) & 1u)) >> 16);
}
__device__ __forceinline__ float bf2f(unsigned short s) {
    return __uint_as_float(((unsigned)s) << 16);
}
__device__ __forceinline__ float sigf(float x) { return 1.f / (1.f + expf(-x)); }

__device__ __forceinline__ void split3(float v, unsigned short& s0,
                                       unsigned short& s1, unsigned short& s2) {
    s0 = f2bf(v); float f0 = bf2f(s0);
    s1 = f2bf(v - f0); float f1 = bf2f(s1);
    s2 = f2bf(v - f0 - f1);
}

__device__ __forceinline__ void gl16(const unsigned short* g, unsigned short* l) {
    __builtin_amdgcn_global_load_lds((const __attribute__((address_space(1))) void*)g,
                                     (__attribute__((address_space(3))) void*)l, 16, 0, 0);
}

// LDS tile: [rows][64] bf16, row = 128B, 16B-units XOR-swizzled by (row&7)
__device__ __forceinline__ short8v fragld(const unsigned short* sh, int row, int uw) {
    return *(const short8v*)(sh + row * 64 + ((uw ^ (row & 7)) << 3));
}

// pre staging (512 threads): one kr chunk = A 3 splits (128 rows) + B 3 (64)
__device__ __forceinline__ void stage_pre(const unsigned short* Ag,
                                          const unsigned short* Bg,
                                          int kr, unsigned short* slot, int tid)
{
#pragma unroll
    for (int s = 0; s < 3; ++s)
#pragma unroll
        for (int v = 0; v < 2; ++v) {
            int e = v * 512 + tid;     // 0..1023 = 128 rows x 8 units
            gl16(Ag + (size_t)(e >> 3) * KP_PRE + s * 640 + kr * 64 + (e & 7) * 8,
                 slot + s * 8192 + e * 8);
        }
#pragma unroll
    for (int s = 0; s < 3; ++s) {
        int e = tid;                   // 0..511 = 64 rows x 8 units
        gl16(Bg + (size_t)(e >> 3) * KP_PRE + s * 640 + kr * 64 + (e & 7) * 8,
             slot + 24576 + s * 4096 + e * 8);
    }
}

// z-path staging, 512-thread variant: one gl16 per split per thread
__device__ __forceinline__ void stageA3w(const unsigned short* Ag, int kr,
                                         unsigned short* buf, int tid)
{
#pragma unroll
    for (int s = 0; s < 3; ++s) {
        int e = tid;   // 0..511 = 64 rows x 8 units
        gl16(Ag + (size_t)(e >> 3) * KP_HS + (s * 8 + kr) * 64 + (e & 7) * 8,
             buf + s * 4096 + e * 8);
    }
}
__device__ __forceinline__ void stageB3w(const unsigned short* Bg, int kr,
                                         unsigned short* buf, int tid)
{
#pragma unroll
    for (int s = 0; s < 3; ++s) {
        int e = tid;
        gl16(Bg + (size_t)(e >> 3) * KP_HS + (s * 8 + kr) * 64 + (e & 7) * 8,
             buf + 12288 + s * 4096 + e * 8);
    }
}
__device__ __forceinline__ void stage6w(const unsigned short* Ag,
                                        const unsigned short* Bg,
                                        int kr, unsigned short* buf, int tid)
{
    stageA3w(Ag, kr, buf, tid);
    stageB3w(Bg, kr, buf, tid);
}

// ---------------- builders --------------------------------------------------
__global__ __launch_bounds__(256) void build_Xb(const float* __restrict__ fp,
                                                const float* __restrict__ gt)
{
    const int tid = threadIdx.x;
    const int m  = blockIdx.x * 16 + (tid >> 4);
    const int k8 = (blockIdx.y * 16 + (tid & 15)) * 8;
    const int t = m >> 9, b = m & 511;
    float x[8];
    if (k8 < 512) {
        float4 v0 = *(const float4*)(fp + ((size_t)(b * 32 + t)) * 512 + k8);
        float4 v1 = *(const float4*)(fp + ((size_t)(b * 32 + t)) * 512 + k8 + 4);
        x[0]=v0.x; x[1]=v0.y; x[2]=v0.z; x[3]=v0.w;
        x[4]=v1.x; x[5]=v1.y; x[6]=v1.z; x[7]=v1.w;
    } else if (t > 0) {
        float4 v0 = *(const float4*)(gt + ((size_t)(b * 32 + t - 1)) * 128 + (k8 - 512));
        float4 v1 = *(const float4*)(gt + ((size_t)(b * 32 + t - 1)) * 128 + (k8 - 512) + 4);
        x[0]=v0.x; x[1]=v0.y; x[2]=v0.z; x[3]=v0.w;
        x[4]=v1.x; x[5]=v1.y; x[6]=v1.z; x[7]=v1.w;
    } else {
#pragma unroll
        for (int j = 0; j < 8; ++j) x[j] = 0.f;
    }
    unsigned short s0[8], s1[8], s2[8];
#pragma unroll
    for (int j = 0; j < 8; ++j) split3(x[j], s0[j], s1[j], s2[j]);
    const int u = (k8 >> 3) & 7;
    const int base = (k8 & ~63) + (((u ^ (m & 7))) << 3);
    ushort8v v0, v1, v2;
#pragma unroll
    for (int j = 0; j < 8; ++j) { v0[j] = s0[j]; v1[j] = s1[j]; v2[j] = s2[j]; }
    *(ushort8v*)&g_Xb[m][0 * 640 + base] = v0;
    *(ushort8v*)&g_Xb[m][1 * 640 + base] = v1;
    *(ushort8v*)&g_Xb[m][2 * 640 + base] = v2;
}

__global__ __launch_bounds__(256) void build_Wb(const float* __restrict__ Wk)
{
    const int tid = threadIdx.x;
    const int np = blockIdx.x * 16 + (tid >> 4);
    const int k8 = (blockIdx.y * 16 + (tid & 15)) * 8;
    const int n = (np & 3) * 512 + (np >> 2);
    float x[8];
#pragma unroll
    for (int j = 0; j < 8; ++j) x[j] = Wk[(size_t)(k8 + j) * 2048 + n];
    unsigned short s0[8], s1[8], s2[8];
#pragma unroll
    for (int j = 0; j < 8; ++j) split3(x[j], s0[j], s1[j], s2[j]);
    const int u = (k8 >> 3) & 7;
    const int base = (k8 & ~63) + (((u ^ (np & 7))) << 3);
    ushort8v v0, v1, v2;
#pragma unroll
    for (int j = 0; j < 8; ++j) { v0[j] = s0[j]; v1[j] = s1[j]; v2[j] = s2[j]; }
    *(ushort8v*)&g_Wb[np][0 * 640 + base] = v0;
    *(ushort8v*)&g_Wb[np][1 * 640 + base] = v1;
    *(ushort8v*)&g_Wb[np][2 * 640 + base] = v2;
}

__global__ __launch_bounds__(256) void build_Rb(const float* __restrict__ Rk)
{
    const int tid = threadIdx.x;
    const int np = blockIdx.x * 16 + (tid >> 4);
    const int k8 = (blockIdx.y * 16 + (tid & 15)) * 8;
    const int n = (np & 3) * 512 + (np >> 2);
    float x[8];
#pragma unroll
    for (int j = 0; j < 8; ++j) x[j] = Rk[(size_t)(k8 + j) * 2048 + n];
    unsigned short s0[8], s1[8], s2[8];
#pragma unroll
    for (int j = 0; j < 8; ++j) split3(x[j], s0[j], s1[j], s2[j]);
    const int u = (k8 >> 3) & 7;
    const int base = (k8 & ~63) + (((u ^ (np & 7))) << 3);
    ushort8v v0, v1, v2;
#pragma unroll
    for (int j = 0; j < 8; ++j) { v0[j] = s0[j]; v1[j] = s1[j]; v2[j] = s2[j]; }
    *(ushort8v*)&g_Rb[np][0 * 512 + base] = v0;
    *(ushort8v*)&g_Rb[np][1 * 512 + base] = v1;
    *(ushort8v*)&g_Rb[np][2 * 512 + base] = v2;
}

__global__ __launch_bounds__(256) void build_misc(const float* __restrict__ sw,
                                                  const float* __restrict__ bias)
{
    int id = blockIdx.x * 256 + threadIdx.x;
    if (id < 128 * 512) {
        int c = id >> 9, r = id & 511;
        g_swT[c][r] = sw[(size_t)r * 128 + c];
    } else if (id < 128 * 512 + 2048) {
        int np = id - 128 * 512;
        g_bperm[np] = bias[(np & 3) * 512 + (np >> 2)];
    }
}

// ---------------- PRE = x@K + bias (compact 3-split, 512t, 2 waves/SIMD) -----
__global__ __launch_bounds__(512, 1) void pre_mfma()
{
    __shared__ __align__(16) char smem[147456];    // 2 slots x 72 KB
    const int tid = threadIdx.x, lane = tid & 63, wave = tid >> 6;   // 8 waves
    // XCD swizzle (R11 proven): all 32 n-blocks of one m-row on ONE XCD.
    const int vid = blockIdx.y * 32 + blockIdx.x;   // dispatch-linear id
    const int x8 = vid & 7, k = vid >> 3;           // XCD, index within XCD
    const int m0 = (x8 + 8 * (k >> 5)) * 128;       // 16 m-rows per XCD
    const int n0 = (k & 31) * 64;
    // 8-wave split 2x4: wr in {0,1} -> 64 rows (4 frags); wc in 0..3 -> 16 cols
    const int wr = wave >> 2, wc = wave & 3, l15 = lane & 15, ql = lane >> 4;
    unsigned short* ring = (unsigned short*)smem;
    const unsigned short* Ag = &g_Xb[m0][0];
    const unsigned short* Bg = &g_Wb[n0][0];

    constexpr int ipt[6] = {0, 0, 1, 0, 1, 2};
    constexpr int jpt[6] = {0, 1, 0, 2, 1, 0};

    f32x4 acc[4];
#pragma unroll
    for (int a = 0; a < 4; ++a) acc[a] = (f32x4){0.f, 0.f, 0.f, 0.f};

    stage_pre(Ag, Bg, 0, ring, tid);
    stage_pre(Ag, Bg, 1, ring + 36864, tid);
    for (int kr = 0; kr < 10; ++kr) {
        if (kr <= 8) WAITV(9);       // next chunk's 9 loads stay in flight
        else         WAITV(0);
        SBAR();
        const unsigned short* Ab = ring + (kr & 1) * 36864;
        const unsigned short* Bb = Ab + 24576;
#pragma unroll
        for (int sub = 0; sub < 2; ++sub) {
            const int uw = sub * 4 + ql;
            short8v a0[4], a1[4], a2[4], b0, b1, b2;
#pragma unroll
            for (int fa = 0; fa < 4; ++fa) {
                a0[fa] = fragld(Ab + 0 * 8192, wr * 64 + fa * 16 + l15, uw);
                a1[fa] = fragld(Ab + 1 * 8192, wr * 64 + fa * 16 + l15, uw);
                a2[fa] = fragld(Ab + 2 * 8192, wr * 64 + fa * 16 + l15, uw);
            }
            b0 = fragld(Bb + 0 * 4096, wc * 16 + l15, uw);
            b1 = fragld(Bb + 1 * 4096, wc * 16 + l15, uw);
            b2 = fragld(Bb + 2 * 4096, wc * 16 + l15, uw);
#pragma unroll
            for (int p = 0; p < 6; ++p) {
                const short8v* A2 = (ipt[p] == 0) ? a0 : ((ipt[p] == 1) ? a1 : a2);
                const short8v  B2 = (jpt[p] == 0) ? b0 : ((jpt[p] == 1) ? b1 : b2);
#pragma unroll
                for (int fa = 0; fa < 4; ++fa)
                    acc[fa] = __builtin_amdgcn_mfma_f32_16x16x32_bf16(
                        A2[fa], B2, acc[fa], 0, 0, 0);
            }
        }
        SBAR();   // all waves done reading slot before restaging it
        if (kr + 2 < 10)
            stage_pre(Ag, Bg, kr + 2, ring + (kr & 1) * 36864, tid);
    }
#pragma unroll
    for (int fa = 0; fa < 4; ++fa) {
        const int np = n0 + wc * 16 + l15;
        const float bv = g_bperm[np];
#pragma unroll
        for (int q = 0; q < 4; ++q) {
            const int m = m0 + wr * 64 + fa * 16 + ql * 4 + q;
            g_pre[m][np] = acc[fa][q] + bv;
        }
    }
}

// ---------------- persistent recurrence (R8/R11 verbatim: XCD-local, 512t) ---
__global__ __launch_bounds__(512, 1) void charnn_rec(
    const float* __restrict__ sb,
    float* __restrict__ seq, float* __restrict__ out_h, float* __restrict__ out_c)
{
    __shared__ __align__(16) char smem[147456];    // 3 ring bufs x 48 KB; zbuf alias
    float (*zbuf)[68] = (float (*)[68])smem;       // 17 KB, inside slot0 A-half
    unsigned short* ring = (unsigned short*)smem;

    const int bi = blockIdx.x, tid = threadIdx.x;
    const int lane = tid & 63, wave = tid >> 6;    // wave 0..7
    const int x  = bi & 7, jj = bi >> 3;
    const int Mg = x;                                // == XCD id
    const int Ng = jj;                               // 0..31
    const int m0 = Mg * 64, n0 = Ng * 64;
    const int wr = wave >> 2, wc = wave & 3, l15 = lane & 15, ql = lane >> 4;

    const int m_e = tid >> 3;            // 0..63
    const int rb2 = (tid & 7) * 2;       // 0,2,..,14
    const int mg = m0 + m_e;
    float cst[2] = {0.f, 0.f};

    const int rgrp = Mg * 4 + (jj & 3);
    const int cg   = jj >> 2;
    const int arow = Mg * 64 + jj * 2;
    const bool xleader = (jj == 0);

    constexpr int ipt[6] = {0, 0, 1, 0, 1, 2};
    constexpr int jpt[6] = {0, 1, 0, 2, 1, 0};

    const unsigned short* Bg = &g_Rb[n0][0];

    f32x4 pqa, pqb;
    {
        const float* prow = &g_pre[0 * 512 + mg][n0];
        pqa = *(const f32x4*)(prow + rb2 * 4);
        pqb = *(const f32x4*)(prow + rb2 * 4 + 4);
    }

    for (int ph = 0; ph < 34; ++ph) {
        const int t = ph;
        const bool do_z = (ph >= 1 && ph <= 31);

        const unsigned short* Ag = nullptr;
        if (do_z) {
            Ag = &g_hs[(t + 1) & 1][m0][0];
            stageA3w(Ag, 0, ring + 0 * 24576, tid);
            stageA3w(Ag, 1, ring + 1 * 24576, tid);
            stageA3w(Ag, 2, ring + 2 * 24576, tid);
        }

        if (ph >= 1 && ph <= 32 && tid < 256) {
            const int tl = ph - 1;
            const int row = rgrp * 16 + (tid >> 4);
            const int col = cg * 16 + (tid & 15);
            const float* hrow = &g_hf[tl & 1][(size_t)row * 512];
            const float* wcol = &g_swT[col][0];
            float s0 = sb[col], s1 = 0.f, s2 = 0.f, s3 = 0.f;
#pragma unroll 8
            for (int k = 0; k < 512; k += 4) {
                float4 hv = *(const float4*)(hrow + k);
                float4 wv = *(const float4*)(wcol + k);
                s0 = fmaf(hv.x, wv.x, s0); s1 = fmaf(hv.y, wv.y, s1);
                s2 = fmaf(hv.z, wv.z, s2); s3 = fmaf(hv.w, wv.w, s3);
            }
            float bv = (s0 + s1) + (s2 + s3); int bidx = col;
#pragma unroll
            for (int m = 1; m < 16; m <<= 1) {
                float ov = __shfl_xor(bv, m, 64);
                int   oi = __shfl_xor(bidx, m, 64);
                if (ov > bv || (ov == bv && oi < bidx)) { bv = ov; bidx = oi; }
            }
            if ((tid & 15) == 0) {
                g_plv[tl & 1][row * 8 + cg] = bv;
                g_pli[tl & 1][row * 8 + cg] = bidx;
            }
        }

        if (ph >= 2 && wave < 2) {
            const int t2 = ph - 2;
            const int row = arow + wave;
            float v; int idx;
            if (lane < 8) {
                v   = g_plv[t2 & 1][row * 8 + lane];
                idx = g_pli[t2 & 1][row * 8 + lane];
            } else { v = -INFINITY; idx = 0x7fffffff; }
#pragma unroll
            for (int m = 1; m < 8; m <<= 1) {
                float ov = __shfl_xor(v, m, 64);
                int   oi = __shfl_xor(idx, m, 64);
                if (ov > v || (ov == v && oi < idx)) { v = ov; idx = oi; }
            }
            int win = __shfl(idx, 0, 64);
            if (lane < 32) {
                int c4 = lane * 4;
                float4 o;
                o.x = (c4 + 0 == win) ? 1.f : 0.f;
                o.y = (c4 + 1 == win) ? 1.f : 0.f;
                o.z = (c4 + 2 == win) ? 1.f : 0.f;
                o.w = (c4 + 3 == win) ? 1.f : 0.f;
                *(float4*)(seq + ((size_t)row * 32 + t2) * 128 + c4) = o;
            }
        }

        if (ph <= 31) {
            if (do_z) {
                f32x4 acc[2];
                acc[0] = (f32x4){0.f, 0.f, 0.f, 0.f};
                acc[1] = (f32x4){0.f, 0.f, 0.f, 0.f};
#pragma unroll
                for (int kr = 0; kr < 8; ++kr) {
                    if (kr >= 1 && kr <= 5)
                        stage6w(Ag, Bg, kr + 2, ring + ((kr + 2) % 3) * 24576, tid);
                    if      (kr == 0) WAITV(6);
                    else if (kr == 1) WAITV(9);
                    else if (kr == 6) WAITV(6);
                    else if (kr == 7) WAITV(0);
                    else              WAITV(12);
                    SBAR();
                    const unsigned short* Ab = ring + (kr % 3) * 24576;
                    const unsigned short* Bb = Ab + 12288;
#pragma unroll
                    for (int sub = 0; sub < 2; ++sub) {
                        const int uw = sub * 4 + ql;
                        short8v a0[2], a1[2], a2[2], b0, b1, b2;
                        a0[0] = fragld(Ab + 0 * 4096, wr * 32 + l15, uw);
                        a0[1] = fragld(Ab + 0 * 4096, wr * 32 + 16 + l15, uw);
                        a1[0] = fragld(Ab + 1 * 4096, wr * 32 + l15, uw);
                        a1[1] = fragld(Ab + 1 * 4096, wr * 32 + 16 + l15, uw);
                        a2[0] = fragld(Ab + 2 * 4096, wr * 32 + l15, uw);
                        a2[1] = fragld(Ab + 2 * 4096, wr * 32 + 16 + l15, uw);
                        b0 = fragld(Bb + 0 * 4096, wc * 16 + l15, uw);
                        b1 = fragld(Bb + 1 * 4096, wc * 16 + l15, uw);
                        b2 = fragld(Bb + 2 * 4096, wc * 16 + l15, uw);
#pragma unroll
                        for (int p = 0; p < 6; ++p) {
                            const short8v* A2 = (ipt[p] == 0) ? a0 :
                                                ((ipt[p] == 1) ? a1 : a2);
                            const short8v  B2 = (jpt[p] == 0) ? b0 :
                                                ((jpt[p] == 1) ? b1 : b2);
                            acc[0] = __builtin_amdgcn_mfma_f32_16x16x32_bf16(
                                A2[0], B2, acc[0], 0, 0, 0);
                            acc[1] = __builtin_amdgcn_mfma_f32_16x16x32_bf16(
                                A2[1], B2, acc[1], 0, 0, 0);
                        }
                    }
                }
                __syncthreads();   // drain ring reads; ring -> zbuf reuse safe
#pragma unroll
                for (int fa = 0; fa < 2; ++fa)
#pragma unroll
                    for (int q2 = 0; q2 < 4; ++q2)
                        zbuf[wr * 32 + fa * 16 + ql * 4 + q2]
                            [wc * 16 + l15] = acc[fa][q2];
            }
            __syncthreads();

            unsigned short hs0[2], hs1[2], hs2[2];
            float hv2[2];
#pragma unroll
            for (int i = 0; i < 2; ++i) {
                const int rl = rb2 + i;
                float zi, zf, zg, zo;
                if (t > 0) {
                    float4 zq = *(const float4*)&zbuf[m_e][rl * 4];
                    zi = zq.x; zf = zq.y; zg = zq.z; zo = zq.w;
                } else { zi = zf = zg = zo = 0.f; }
                f32x4 pq = (i == 0) ? pqa : pqb;
                zi += pq[0]; zf += pq[1]; zg += pq[2]; zo += pq[3];
                float c2 = sigf(zf) * cst[i] + sigf(zi) * tanhf(zg);
                float h2 = sigf(zo) * tanhf(c2);
                cst[i] = c2;
                hv2[i] = h2;
                split3(h2, hs0[i], hs1[i], hs2[i]);
            }
            const int r0g = Ng * 16 + rb2;
            *(float2*)&g_hf[t & 1][(size_t)mg * 512 + r0g] =
                make_float2(hv2[0], hv2[1]);
            if (t == 31) {
                *(float2*)&out_h[(size_t)mg * 512 + r0g] =
                    make_float2(hv2[0], hv2[1]);
                *(float2*)&out_c[(size_t)mg * 512 + r0g] =
                    make_float2(cst[0], cst[1]);
            }
            const int su = ((r0g >> 3) & 7) ^ (mg & 7);
            const int abase = (r0g & ~63) + (su << 3) + (r0g & 7);
#pragma unroll
            for (int i = 0; i < 3; ++i) {
                ushort2v v;
#pragma unroll
                for (int j = 0; j < 2; ++j)
                    v[j] = (i == 0) ? hs0[j] : ((i == 1) ? hs1[j] : hs2[j]);
                *(ushort2v*)&g_hs[t & 1][mg][i * 512 + abase] = v;
            }
        }

        if (ph < 33) {
            __syncthreads();

            if (ph <= 30) {
                stageB3w(Bg, 0, ring + 0 * 24576, tid);
                stageB3w(Bg, 1, ring + 1 * 24576, tid);
                stageB3w(Bg, 2, ring + 2 * 24576, tid);
                const float* prow = &g_pre[(ph + 1) * 512 + mg][n0];
                pqa = *(const f32x4*)(prow + rb2 * 4);
                pqb = *(const f32x4*)(prow + rb2 * 4 + 4);
            }

            if (tid == 0) {
                __hip_atomic_fetch_add(&g_xcnt[x * 16], 1u,
                                       __ATOMIC_RELAXED, __HIP_MEMORY_SCOPE_AGENT);
                if (xleader) {
                    const unsigned xt = 32u * (unsigned)(ph + 1);
                    while (__hip_atomic_load(&g_xcnt[x * 16], __ATOMIC_RELAXED,
                                             __HIP_MEMORY_SCOPE_AGENT) < xt)
                        __builtin_amdgcn_s_sleep(2);
                    __hip_atomic_store(&g_xrel[x * 16], (unsigned)(ph + 1),
                                       __ATOMIC_RELAXED, __HIP_MEMORY_SCOPE_AGENT);
                }
                while (__hip_atomic_load(&g_xrel[x * 16], __ATOMIC_RELAXED,
                                         __HIP_MEMORY_SCOPE_AGENT) < (unsigned)(ph + 1))
                    __builtin_amdgcn_s_sleep(2);
                __builtin_amdgcn_fence(__ATOMIC_ACQUIRE, "agent");
            }
            __syncthreads();
        }
    }
}

// ---------------------------------------------------------------------------
extern "C" void kernel_launch(void* const* d_in, const int* in_sizes, int n_in,
                              void* d_out, int out_size, void* d_ws, size_t ws_size,
                              hipStream_t stream)
{
    const float* fp   = (const float*)d_in[0];  // f_pool       [512,32,512]
    const float* gt   = (const float*)d_in[1];  // ground_truth [512,32,128]
    const float* Wk   = (const float*)d_in[2];  // kernel       [640,2048]
    const float* Rk   = (const float*)d_in[3];  // rec_kernel   [512,2048]
    const float* bias = (const float*)d_in[4];  // [2048]
    const float* sw   = (const float*)d_in[5];  // softmax_w    [512,128]
    const float* sb   = (const float*)d_in[6];  // softmax_b    [128]
    float* seq   = (float*)d_out;                        // [512,32,128]
    float* out_h = seq + (size_t)512 * 32 * 128;         // [512,512]
    float* out_c = out_h + (size_t)512 * 512;            // [512,512]

    hipLaunchKernelGGL(init_counters, dim3(1), dim3(64), 0, stream);
    hipLaunchKernelGGL(build_Xb, dim3(1024, 5), dim3(256), 0, stream, fp, gt);
    hipLaunchKernelGGL(build_Wb, dim3(128, 5), dim3(256), 0, stream, Wk);
    hipLaunchKernelGGL(build_Rb, dim3(128, 4), dim3(256), 0, stream, Rk);
    hipLaunchKernelGGL(build_misc, dim3(264), dim3(256), 0, stream, sw, bias);
    hipLaunchKernelGGL(pre_mfma, dim3(32, 128), dim3(512), 0, stream);
    hipLaunchKernelGGL(charnn_rec, dim3(256), dim3(512), 0, stream,
                       sb, seq, out_h, out_c);
}

// Round 13
// 1382.353 us; speedup vs baseline: 1.2281x; 1.0306x over previous
//
#include <hip/hip_runtime.h>
#include <math.h>

typedef float  f32x4  __attribute__((ext_vector_type(4)));
typedef short  short8v __attribute__((ext_vector_type(8)));
typedef unsigned short ushort8v __attribute__((ext_vector_type(8)));
typedef unsigned short ushort2v __attribute__((ext_vector_type(2)));

#define KP_PRE 1920
#define KP_HS  1536

#define WAITV(N) asm volatile("s_waitcnt vmcnt(" #N ")" ::: "memory")
#define SBAR()   asm volatile("s_barrier" ::: "memory")

// ---------------- persistent device state ----------------------------------
__device__ unsigned short g_Xb[16384][1920];  // pre A (x 3 i-splits, swizzled)
__device__ unsigned short g_Wb[2048][1920];   // pre B^T (kernel 3 j-splits)
__device__ unsigned short g_Rb[2048][1536];   // z   B^T (rec_kernel, 3 j-splits)
__device__ unsigned short g_hs[2][512][1536]; // h 3 i-splits, ping-pong
__device__ float g_pre[16384][2048];          // x@K + bias (gate-interleaved)
__device__ float g_hf[2][512 * 512];          // h f32, ping-pong
__device__ float g_swT[128][512];             // softmax_w transposed
__device__ float g_bperm[2048];               // bias, gate-interleaved cols
__device__ float g_plv[2][512 * 8];
__device__ int   g_pli[2][512 * 8];
__device__ unsigned g_xcnt[128];              // 8 per-XCD arrival counters
__device__ unsigned g_xrel[128];              // 8 per-XCD release flags

// ---------------- helpers ---------------------------------------------------
__device__ __forceinline__ unsigned short f2bf(float f) {
    unsigned u = __float_as_uint(f);
    return (unsigned short)((u + 0x7fffu + ((u >> 16) & 1u)) >> 16);
}
__device__ __forceinline__ float bf2f(unsigned short s) {
    return __uint_as_float(((unsigned)s) << 16);
}
__device__ __forceinline__ float sigf(float x) { return 1.f / (1.f + expf(-x)); }

__device__ __forceinline__ void split3(float v, unsigned short& s0,
                                       unsigned short& s1, unsigned short& s2) {
    s0 = f2bf(v); float f0 = bf2f(s0);
    s1 = f2bf(v - f0); float f1 = bf2f(s1);
    s2 = f2bf(v - f0 - f1);
}

// pair tables: products split_i(A) * split_j(B), i+j <= 2
__device__ __constant__ int c_ipt[6] = {0, 0, 1, 0, 1, 2};
__device__ __constant__ int c_jpt[6] = {0, 1, 0, 2, 1, 0};

__device__ __forceinline__ void gl16(const unsigned short* g, unsigned short* l) {
    __builtin_amdgcn_global_load_lds((const __attribute__((address_space(1))) void*)g,
                                     (__attribute__((address_space(3))) void*)l, 16, 0, 0);
}

// LDS tile: [rows][64] bf16, row = 128B, 16B-units XOR-swizzled by (row&7)
__device__ __forceinline__ short8v fragld(const unsigned short* sh, int row, int uw) {
    return *(const short8v*)(sh + row * 64 + ((uw ^ (row & 7)) << 3));
}

// pre staging (512 threads): one kr chunk = A 3 splits (128 rows) + B 3 (64)
__device__ __forceinline__ void stage_pre(const unsigned short* Ag,
                                          const unsigned short* Bg,
                                          int kr, unsigned short* slot, int tid)
{
#pragma unroll
    for (int s = 0; s < 3; ++s)
#pragma unroll
        for (int v = 0; v < 2; ++v) {
            int e = v * 512 + tid;     // 0..1023 = 128 rows x 8 units
            gl16(Ag + (size_t)(e >> 3) * KP_PRE + s * 640 + kr * 64 + (e & 7) * 8,
                 slot + s * 8192 + e * 8);
        }
#pragma unroll
    for (int s = 0; s < 3; ++s) {
        int e = tid;                   // 0..511 = 64 rows x 8 units
        gl16(Bg + (size_t)(e >> 3) * KP_PRE + s * 640 + kr * 64 + (e & 7) * 8,
             slot + 24576 + s * 4096 + e * 8);
    }
}

// z-path staging, 512-thread variant: one gl16 per split per thread
__device__ __forceinline__ void stageA3w(const unsigned short* Ag, int kr,
                                         unsigned short* buf, int tid)
{
#pragma unroll
    for (int s = 0; s < 3; ++s) {
        int e = tid;   // 0..511 = 64 rows x 8 units
        gl16(Ag + (size_t)(e >> 3) * KP_HS + (s * 8 + kr) * 64 + (e & 7) * 8,
             buf + s * 4096 + e * 8);
    }
}
__device__ __forceinline__ void stageB3w(const unsigned short* Bg, int kr,
                                         unsigned short* buf, int tid)
{
#pragma unroll
    for (int s = 0; s < 3; ++s) {
        int e = tid;
        gl16(Bg + (size_t)(e >> 3) * KP_HS + (s * 8 + kr) * 64 + (e & 7) * 8,
             buf + 12288 + s * 4096 + e * 8);
    }
}
__device__ __forceinline__ void stage6w(const unsigned short* Ag,
                                        const unsigned short* Bg,
                                        int kr, unsigned short* buf, int tid)
{
    stageA3w(Ag, kr, buf, tid);
    stageB3w(Bg, kr, buf, tid);
}

// ---------------- merged builder (bodies verbatim; branch by block range) ----
__global__ __launch_bounds__(256) void build_all(const float* __restrict__ fp,
                                                 const float* __restrict__ gt,
                                                 const float* __restrict__ Wk,
                                                 const float* __restrict__ Rk,
                                                 const float* __restrict__ sw,
                                                 const float* __restrict__ bias)
{
    const int b = blockIdx.x, tid = threadIdx.x;
    if (b < 5120) {                                   // ---- build_Xb ----
        const int bx = b & 1023, by = b >> 10;
        const int m  = bx * 16 + (tid >> 4);
        const int k8 = (by * 16 + (tid & 15)) * 8;
        const int t = m >> 9, bb = m & 511;
        float x[8];
        if (k8 < 512) {
            float4 v0 = *(const float4*)(fp + ((size_t)(bb * 32 + t)) * 512 + k8);
            float4 v1 = *(const float4*)(fp + ((size_t)(bb * 32 + t)) * 512 + k8 + 4);
            x[0]=v0.x; x[1]=v0.y; x[2]=v0.z; x[3]=v0.w;
            x[4]=v1.x; x[5]=v1.y; x[6]=v1.z; x[7]=v1.w;
        } else if (t > 0) {
            float4 v0 = *(const float4*)(gt + ((size_t)(bb * 32 + t - 1)) * 128 + (k8 - 512));
            float4 v1 = *(const float4*)(gt + ((size_t)(bb * 32 + t - 1)) * 128 + (k8 - 512) + 4);
            x[0]=v0.x; x[1]=v0.y; x[2]=v0.z; x[3]=v0.w;
            x[4]=v1.x; x[5]=v1.y; x[6]=v1.z; x[7]=v1.w;
        } else {
#pragma unroll
            for (int j = 0; j < 8; ++j) x[j] = 0.f;
        }
        unsigned short s0[8], s1[8], s2[8];
#pragma unroll
        for (int j = 0; j < 8; ++j) split3(x[j], s0[j], s1[j], s2[j]);
        const int u = (k8 >> 3) & 7;
        const int base = (k8 & ~63) + (((u ^ (m & 7))) << 3);
        ushort8v v0, v1, v2;
#pragma unroll
        for (int j = 0; j < 8; ++j) { v0[j] = s0[j]; v1[j] = s1[j]; v2[j] = s2[j]; }
        *(ushort8v*)&g_Xb[m][0 * 640 + base] = v0;
        *(ushort8v*)&g_Xb[m][1 * 640 + base] = v1;
        *(ushort8v*)&g_Xb[m][2 * 640 + base] = v2;
    } else if (b < 5760) {                            // ---- build_Wb ----
        const int ib = b - 5120;
        const int bx = ib & 127, by = ib >> 7;
        const int np = bx * 16 + (tid >> 4);
        const int k8 = (by * 16 + (tid & 15)) * 8;
        const int n = (np & 3) * 512 + (np >> 2);
        float x[8];
#pragma unroll
        for (int j = 0; j < 8; ++j) x[j] = Wk[(size_t)(k8 + j) * 2048 + n];
        unsigned short s0[8], s1[8], s2[8];
#pragma unroll
        for (int j = 0; j < 8; ++j) split3(x[j], s0[j], s1[j], s2[j]);
        const int u = (k8 >> 3) & 7;
        const int base = (k8 & ~63) + (((u ^ (np & 7))) << 3);
        ushort8v v0, v1, v2;
#pragma unroll
        for (int j = 0; j < 8; ++j) { v0[j] = s0[j]; v1[j] = s1[j]; v2[j] = s2[j]; }
        *(ushort8v*)&g_Wb[np][0 * 640 + base] = v0;
        *(ushort8v*)&g_Wb[np][1 * 640 + base] = v1;
        *(ushort8v*)&g_Wb[np][2 * 640 + base] = v2;
    } else if (b < 6272) {                            // ---- build_Rb ----
        const int ib = b - 5760;
        const int bx = ib & 127, by = ib >> 7;
        const int np = bx * 16 + (tid >> 4);
        const int k8 = (by * 16 + (tid & 15)) * 8;
        const int n = (np & 3) * 512 + (np >> 2);
        float x[8];
#pragma unroll
        for (int j = 0; j < 8; ++j) x[j] = Rk[(size_t)(k8 + j) * 2048 + n];
        unsigned short s0[8], s1[8], s2[8];
#pragma unroll
        for (int j = 0; j < 8; ++j) split3(x[j], s0[j], s1[j], s2[j]);
        const int u = (k8 >> 3) & 7;
        const int base = (k8 & ~63) + (((u ^ (np & 7))) << 3);
        ushort8v v0, v1, v2;
#pragma unroll
        for (int j = 0; j < 8; ++j) { v0[j] = s0[j]; v1[j] = s1[j]; v2[j] = s2[j]; }
        *(ushort8v*)&g_Rb[np][0 * 512 + base] = v0;
        *(ushort8v*)&g_Rb[np][1 * 512 + base] = v1;
        *(ushort8v*)&g_Rb[np][2 * 512 + base] = v2;
    } else if (b < 6536) {                            // ---- build_misc ----
        int id = (b - 6272) * 256 + tid;
        if (id < 128 * 512) {
            int c = id >> 9, r = id & 511;
            g_swT[c][r] = sw[(size_t)r * 128 + c];
        } else if (id < 128 * 512 + 2048) {
            int np = id - 128 * 512;
            g_bperm[np] = bias[(np & 3) * 512 + (np >> 2)];
        }
    } else {                                          // ---- init counters ----
        if (tid < 8) { g_xcnt[tid * 16] = 0u; g_xrel[tid * 16] = 0u; }
    }
}

// ---------------- PRE: persistent, continuous 160-chunk ring -----------------
// 256 blocks (1/CU). Block = one m-row (128 rows, A panel 492 KB L2-resident)
// x 16 n-tiles (half of 32; 2 blocks per m-row). The kr ring never drains
// between tiles: WAITV(9) throughout -> ONE pipeline fill per CU instead of 16.
__global__ __launch_bounds__(512, 1) void pre_mfma()
{
    __shared__ __align__(16) char smem[147456];    // 2 slots x 72 KB
    const int tid = threadIdx.x, lane = tid & 63, wave = tid >> 6;   // 8 waves
    const int bi = blockIdx.x;                      // 0..255
    const int x8 = bi & 7, r = bi >> 3;             // XCD, 0..31
    const int M  = x8 + 8 * (r >> 1);               // m-row 0..127 (XCD-local)
    const int half = r & 1;                         // n-half: tiles 0-15 / 16-31
    const int m0 = M * 128;
    const int wr = wave >> 2, wc = wave & 3, l15 = lane & 15, ql = lane >> 4;
    unsigned short* ring = (unsigned short*)smem;
    const unsigned short* Ag = &g_Xb[m0][0];

    constexpr int ipt[6] = {0, 0, 1, 0, 1, 2};
    constexpr int jpt[6] = {0, 1, 0, 2, 1, 0};

    f32x4 acc[4];

    // chunk c = tile*10 + kr, c in [0,160)
    stage_pre(Ag, &g_Wb[(half * 16 + 0) * 64][0], 0, ring + 0 * 36864, tid);
    stage_pre(Ag, &g_Wb[(half * 16 + 0) * 64][0], 1, ring + 1 * 36864, tid);
    for (int c = 0; c < 160; ++c) {
        const int kr = c - (c / 10) * 10;           // c % 10
        const int tile = c / 10;
        const int n0 = (half * 16 + tile) * 64;
        if (kr == 0) {
#pragma unroll
            for (int a = 0; a < 4; ++a) acc[a] = (f32x4){0.f, 0.f, 0.f, 0.f};
        }
        if (c < 159) WAITV(9);       // next chunk's 9 loads stay in flight
        else         WAITV(0);
        SBAR();
        const unsigned short* Ab = ring + (c & 1) * 36864;
        const unsigned short* Bb = Ab + 24576;
#pragma unroll
        for (int sub = 0; sub < 2; ++sub) {
            const int uw = sub * 4 + ql;
            short8v a0[4], a1[4], a2[4], b0, b1, b2;
#pragma unroll
            for (int fa = 0; fa < 4; ++fa) {
                a0[fa] = fragld(Ab + 0 * 8192, wr * 64 + fa * 16 + l15, uw);
                a1[fa] = fragld(Ab + 1 * 8192, wr * 64 + fa * 16 + l15, uw);
                a2[fa] = fragld(Ab + 2 * 8192, wr * 64 + fa * 16 + l15, uw);
            }
            b0 = fragld(Bb + 0 * 4096, wc * 16 + l15, uw);
            b1 = fragld(Bb + 1 * 4096, wc * 16 + l15, uw);
            b2 = fragld(Bb + 2 * 4096, wc * 16 + l15, uw);
#pragma unroll
            for (int p = 0; p < 6; ++p) {
                const short8v* A2 = (ipt[p] == 0) ? a0 : ((ipt[p] == 1) ? a1 : a2);
                const short8v  B2 = (jpt[p] == 0) ? b0 : ((jpt[p] == 1) ? b1 : b2);
#pragma unroll
                for (int fa = 0; fa < 4; ++fa)
                    acc[fa] = __builtin_amdgcn_mfma_f32_16x16x32_bf16(
                        A2[fa], B2, acc[fa], 0, 0, 0);
            }
        }
        SBAR();   // all waves done reading slot before restaging it
        if (c + 2 < 160) {
            const int c2 = c + 2;
            const int t2 = c2 / 10;
            stage_pre(Ag, &g_Wb[(half * 16 + t2) * 64][0], c2 - t2 * 10,
                      ring + (c2 & 1) * 36864, tid);
        }
        if (kr == 9) {
#pragma unroll
            for (int fa = 0; fa < 4; ++fa) {
                const int np = n0 + wc * 16 + l15;
                const float bv = g_bperm[np];
#pragma unroll
                for (int q = 0; q < 4; ++q) {
                    const int m = m0 + wr * 64 + fa * 16 + ql * 4 + q;
                    g_pre[m][np] = acc[fa][q] + bv;
                }
            }
        }
    }
}

// ---------------- persistent recurrence (R8/R12 verbatim: XCD-local, 512t) ---
__global__ __launch_bounds__(512, 1) void charnn_rec(
    const float* __restrict__ sb,
    float* __restrict__ seq, float* __restrict__ out_h, float* __restrict__ out_c)
{
    __shared__ __align__(16) char smem[147456];    // 3 ring bufs x 48 KB; zbuf alias
    float (*zbuf)[68] = (float (*)[68])smem;       // 17 KB, inside slot0 A-half
    unsigned short* ring = (unsigned short*)smem;

    const int bi = blockIdx.x, tid = threadIdx.x;
    const int lane = tid & 63, wave = tid >> 6;    // wave 0..7
    const int x  = bi & 7, jj = bi >> 3;
    const int Mg = x;                                // == XCD id
    const int Ng = jj;                               // 0..31
    const int m0 = Mg * 64, n0 = Ng * 64;
    const int wr = wave >> 2, wc = wave & 3, l15 = lane & 15, ql = lane >> 4;

    const int m_e = tid >> 3;            // 0..63
    const int rb2 = (tid & 7) * 2;       // 0,2,..,14
    const int mg = m0 + m_e;
    float cst[2] = {0.f, 0.f};

    const int rgrp = Mg * 4 + (jj & 3);
    const int cg   = jj >> 2;
    const int arow = Mg * 64 + jj * 2;
    const bool xleader = (jj == 0);

    constexpr int ipt[6] = {0, 0, 1, 0, 1, 2};
    constexpr int jpt[6] = {0, 1, 0, 2, 1, 0};

    const unsigned short* Bg = &g_Rb[n0][0];

    f32x4 pqa, pqb;
    {
        const float* prow = &g_pre[0 * 512 + mg][n0];
        pqa = *(const f32x4*)(prow + rb2 * 4);
        pqb = *(const f32x4*)(prow + rb2 * 4 + 4);
    }

    for (int ph = 0; ph < 34; ++ph) {
        const int t = ph;
        const bool do_z = (ph >= 1 && ph <= 31);

        const unsigned short* Ag = nullptr;
        if (do_z) {
            Ag = &g_hs[(t + 1) & 1][m0][0];
            stageA3w(Ag, 0, ring + 0 * 24576, tid);
            stageA3w(Ag, 1, ring + 1 * 24576, tid);
            stageA3w(Ag, 2, ring + 2 * 24576, tid);
        }

        if (ph >= 1 && ph <= 32 && tid < 256) {
            const int tl = ph - 1;
            const int row = rgrp * 16 + (tid >> 4);
            const int col = cg * 16 + (tid & 15);
            const float* hrow = &g_hf[tl & 1][(size_t)row * 512];
            const float* wcol = &g_swT[col][0];
            float s0 = sb[col], s1 = 0.f, s2 = 0.f, s3 = 0.f;
#pragma unroll 8
            for (int k = 0; k < 512; k += 4) {
                float4 hv = *(const float4*)(hrow + k);
                float4 wv = *(const float4*)(wcol + k);
                s0 = fmaf(hv.x, wv.x, s0); s1 = fmaf(hv.y, wv.y, s1);
                s2 = fmaf(hv.z, wv.z, s2); s3 = fmaf(hv.w, wv.w, s3);
            }
            float bv = (s0 + s1) + (s2 + s3); int bidx = col;
#pragma unroll
            for (int m = 1; m < 16; m <<= 1) {
                float ov = __shfl_xor(bv, m, 64);
                int   oi = __shfl_xor(bidx, m, 64);
                if (ov > bv || (ov == bv && oi < bidx)) { bv = ov; bidx = oi; }
            }
            if ((tid & 15) == 0) {
                g_plv[tl & 1][row * 8 + cg] = bv;
                g_pli[tl & 1][row * 8 + cg] = bidx;
            }
        }

        if (ph >= 2 && wave < 2) {
            const int t2 = ph - 2;
            const int row = arow + wave;
            float v; int idx;
            if (lane < 8) {
                v   = g_plv[t2 & 1][row * 8 + lane];
                idx = g_pli[t2 & 1][row * 8 + lane];
            } else { v = -INFINITY; idx = 0x7fffffff; }
#pragma unroll
            for (int m = 1; m < 8; m <<= 1) {
                float ov = __shfl_xor(v, m, 64);
                int   oi = __shfl_xor(idx, m, 64);
                if (ov > v || (ov == v && oi < idx)) { v = ov; idx = oi; }
            }
            int win = __shfl(idx, 0, 64);
            if (lane < 32) {
                int c4 = lane * 4;
                float4 o;
                o.x = (c4 + 0 == win) ? 1.f : 0.f;
                o.y = (c4 + 1 == win) ? 1.f : 0.f;
                o.z = (c4 + 2 == win) ? 1.f : 0.f;
                o.w = (c4 + 3 == win) ? 1.f : 0.f;
                *(float4*)(seq + ((size_t)row * 32 + t2) * 128 + c4) = o;
            }
        }

        if (ph <= 31) {
            if (do_z) {
                f32x4 acc[2];
                acc[0] = (f32x4){0.f, 0.f, 0.f, 0.f};
                acc[1] = (f32x4){0.f, 0.f, 0.f, 0.f};
#pragma unroll
                for (int kr = 0; kr < 8; ++kr) {
                    if (kr >= 1 && kr <= 5)
                        stage6w(Ag, Bg, kr + 2, ring + ((kr + 2) % 3) * 24576, tid);
                    if      (kr == 0) WAITV(6);
                    else if (kr == 1) WAITV(9);
                    else if (kr == 6) WAITV(6);
                    else if (kr == 7) WAITV(0);
                    else              WAITV(12);
                    SBAR();
                    const unsigned short* Ab = ring + (kr % 3) * 24576;
                    const unsigned short* Bb = Ab + 12288;
#pragma unroll
                    for (int sub = 0; sub < 2; ++sub) {
                        const int uw = sub * 4 + ql;
                        short8v a0[2], a1[2], a2[2], b0, b1, b2;
                        a0[0] = fragld(Ab + 0 * 4096, wr * 32 + l15, uw);
                        a0[1] = fragld(Ab + 0 * 4096, wr * 32 + 16 + l15, uw);
                        a1[0] = fragld(Ab + 1 * 4096, wr * 32 + l15, uw);
                        a1[1] = fragld(Ab + 1 * 4096, wr * 32 + 16 + l15, uw);
                        a2[0] = fragld(Ab + 2 * 4096, wr * 32 + l15, uw);
                        a2[1] = fragld(Ab + 2 * 4096, wr * 32 + 16 + l15, uw);
                        b0 = fragld(Bb + 0 * 4096, wc * 16 + l15, uw);
                        b1 = fragld(Bb + 1 * 4096, wc * 16 + l15, uw);
                        b2 = fragld(Bb + 2 * 4096, wc * 16 + l15, uw);
#pragma unroll
                        for (int p = 0; p < 6; ++p) {
                            const short8v* A2 = (ipt[p] == 0) ? a0 :
                                                ((ipt[p] == 1) ? a1 : a2);
                            const short8v  B2 = (jpt[p] == 0) ? b0 :
                                                ((jpt[p] == 1) ? b1 : b2);
                            acc[0] = __builtin_amdgcn_mfma_f32_16x16x32_bf16(
                                A2[0], B2, acc[0], 0, 0, 0);
                            acc[1] = __builtin_amdgcn_mfma_f32_16x16x32_bf16(
                                A2[1], B2, acc[1], 0, 0, 0);
                        }
                    }
                }
                __syncthreads();   // drain ring reads; ring -> zbuf reuse safe
#pragma unroll
                for (int fa = 0; fa < 2; ++fa)
#pragma unroll
                    for (int q2 = 0; q2 < 4; ++q2)
                        zbuf[wr * 32 + fa * 16 + ql * 4 + q2]
                            [wc * 16 + l15] = acc[fa][q2];
            }
            __syncthreads();

            unsigned short hs0[2], hs1[2], hs2[2];
            float hv2[2];
#pragma unroll
            for (int i = 0; i < 2; ++i) {
                const int rl = rb2 + i;
                float zi, zf, zg, zo;
                if (t > 0) {
                    float4 zq = *(const float4*)&zbuf[m_e][rl * 4];
                    zi = zq.x; zf = zq.y; zg = zq.z; zo = zq.w;
                } else { zi = zf = zg = zo = 0.f; }
                f32x4 pq = (i == 0) ? pqa : pqb;
                zi += pq[0]; zf += pq[1]; zg += pq[2]; zo += pq[3];
                float c2 = sigf(zf) * cst[i] + sigf(zi) * tanhf(zg);
                float h2 = sigf(zo) * tanhf(c2);
                cst[i] = c2;
                hv2[i] = h2;
                split3(h2, hs0[i], hs1[i], hs2[i]);
            }
            const int r0g = Ng * 16 + rb2;
            *(float2*)&g_hf[t & 1][(size_t)mg * 512 + r0g] =
                make_float2(hv2[0], hv2[1]);
            if (t == 31) {
                *(float2*)&out_h[(size_t)mg * 512 + r0g] =
                    make_float2(hv2[0], hv2[1]);
                *(float2*)&out_c[(size_t)mg * 512 + r0g] =
                    make_float2(cst[0], cst[1]);
            }
            const int su = ((r0g >> 3) & 7) ^ (mg & 7);
            const int abase = (r0g & ~63) + (su << 3) + (r0g & 7);
#pragma unroll
            for (int i = 0; i < 3; ++i) {
                ushort2v v;
#pragma unroll
                for (int j = 0; j < 2; ++j)
                    v[j] = (i == 0) ? hs0[j] : ((i == 1) ? hs1[j] : hs2[j]);
                *(ushort2v*)&g_hs[t & 1][mg][i * 512 + abase] = v;
            }
        }

        if (ph < 33) {
            __syncthreads();

            if (ph <= 30) {
                stageB3w(Bg, 0, ring + 0 * 24576, tid);
                stageB3w(Bg, 1, ring + 1 * 24576, tid);
                stageB3w(Bg, 2, ring + 2 * 24576, tid);
                const float* prow = &g_pre[(ph + 1) * 512 + mg][n0];
                pqa = *(const f32x4*)(prow + rb2 * 4);
                pqb = *(const f32x4*)(prow + rb2 * 4 + 4);
            }

            if (tid == 0) {
                __hip_atomic_fetch_add(&g_xcnt[x * 16], 1u,
                                       __ATOMIC_RELAXED, __HIP_MEMORY_SCOPE_AGENT);
                if (xleader) {
                    const unsigned xt = 32u * (unsigned)(ph + 1);
                    while (__hip_atomic_load(&g_xcnt[x * 16], __ATOMIC_RELAXED,
                                             __HIP_MEMORY_SCOPE_AGENT) < xt)
                        __builtin_amdgcn_s_sleep(2);
                    __hip_atomic_store(&g_xrel[x * 16], (unsigned)(ph + 1),
                                       __ATOMIC_RELAXED, __HIP_MEMORY_SCOPE_AGENT);
                }
                while (__hip_atomic_load(&g_xrel[x * 16], __ATOMIC_RELAXED,
                                         __HIP_MEMORY_SCOPE_AGENT) < (unsigned)(ph + 1))
                    __builtin_amdgcn_s_sleep(2);
                __builtin_amdgcn_fence(__ATOMIC_ACQUIRE, "agent");
            }
            __syncthreads();
        }
    }
}

// ---------------------------------------------------------------------------
extern "C" void kernel_launch(void* const* d_in, const int* in_sizes, int n_in,
                              void* d_out, int out_size, void* d_ws, size_t ws_size,
                              hipStream_t stream)
{
    const float* fp   = (const float*)d_in[0];  // f_pool       [512,32,512]
    const float* gt   = (const float*)d_in[1];  // ground_truth [512,32,128]
    const float* Wk   = (const float*)d_in[2];  // kernel       [640,2048]
    const float* Rk   = (const float*)d_in[3];  // rec_kernel   [512,2048]
    const float* bias = (const float*)d_in[4];  // [2048]
    const float* sw   = (const float*)d_in[5];  // softmax_w    [512,128]
    const float* sb   = (const float*)d_in[6];  // softmax_b    [128]
    float* seq   = (float*)d_out;                        // [512,32,128]
    float* out_h = seq + (size_t)512 * 32 * 128;         // [512,512]
    float* out_c = out_h + (size_t)512 * 512;            // [512,512]

    hipLaunchKernelGGL(build_all, dim3(6537), dim3(256), 0, stream,
                       fp, gt, Wk, Rk, sw, bias);
    hipLaunchKernelGGL(pre_mfma, dim3(256), dim3(512), 0, stream);
    hipLaunchKernelGGL(charnn_rec, dim3(256), dim3(512), 0, stream,
                       sb, seq, out_h, out_c);
}

// Round 14
// 1380.231 us; speedup vs baseline: 1.2299x; 1.0015x over previous
//
#include <hip/hip_runtime.h>
#include <math.h>

typedef float  f32x4  __attribute__((ext_vector_type(4)));
typedef short  short8v __attribute__((ext_vector_type(8)));
typedef unsigned short ushort8v __attribute__((ext_vector_type(8)));
typedef unsigned short ushort2v __attribute__((ext_vector_type(2)));

#define KP_PRE 1920
#define KP_HS  1536

#define WAITV(N) asm volatile("s_waitcnt vmcnt(" #N ")" ::: "memory")
#define SBAR()   asm volatile("s_barrier" ::: "memory")

// ---------------- persistent device state ----------------------------------
__device__ unsigned short g_Xb[16384][1920];  // pre A (x 3 i-splits, swizzled)
__device__ unsigned short g_Wb[2048][1920];   // pre B^T (kernel 3 j-splits)
__device__ unsigned short g_Rb[2048][1536];   // z   B^T (rec_kernel, 3 j-splits)
__device__ unsigned short g_hs[2][512][1536]; // h 3 i-splits, ping-pong
__device__ float g_pre[16384][2048];          // x@K + bias (gate-interleaved)
__device__ float g_hf[2][512 * 512];          // h f32, ping-pong
__device__ float g_swT[128][512];             // softmax_w transposed
__device__ float g_bperm[2048];               // bias, gate-interleaved cols
__device__ float g_plv[2][512 * 8];
__device__ int   g_pli[2][512 * 8];
__device__ unsigned g_xcnt[128];              // 8 per-XCD arrival counters
__device__ unsigned g_xrel[128];              // 8 per-XCD release flags

// ---------------- helpers ---------------------------------------------------
__device__ __forceinline__ unsigned short f2bf(float f) {
    unsigned u = __float_as_uint(f);
    return (unsigned short)((u + 0x7fffu + ((u >> 16) & 1u)) >> 16);
}
__device__ __forceinline__ float bf2f(unsigned short s) {
    return __uint_as_float(((unsigned)s) << 16);
}
__device__ __forceinline__ float sigf(float x) { return 1.f / (1.f + expf(-x)); }

__device__ __forceinline__ void split3(float v, unsigned short& s0,
                                       unsigned short& s1, unsigned short& s2) {
    s0 = f2bf(v); float f0 = bf2f(s0);
    s1 = f2bf(v - f0); float f1 = bf2f(s1);
    s2 = f2bf(v - f0 - f1);
}

// pair tables: products split_i(A) * split_j(B), i+j <= 2
__device__ __constant__ int c_ipt[6] = {0, 0, 1, 0, 1, 2};
__device__ __constant__ int c_jpt[6] = {0, 1, 0, 2, 1, 0};

__device__ __forceinline__ void gl16(const unsigned short* g, unsigned short* l) {
    __builtin_amdgcn_global_load_lds((const __attribute__((address_space(1))) void*)g,
                                     (__attribute__((address_space(3))) void*)l, 16, 0, 0);
}

// LDS tile: [rows][64] bf16, row = 128B, 16B-units XOR-swizzled by (row&7)
__device__ __forceinline__ short8v fragld(const unsigned short* sh, int row, int uw) {
    return *(const short8v*)(sh + row * 64 + ((uw ^ (row & 7)) << 3));
}

// pre staging (512 threads): one kr chunk = A 3 splits (128 rows) + B 3 (64)
__device__ __forceinline__ void stage_pre(const unsigned short* Ag,
                                          const unsigned short* Bg,
                                          int kr, unsigned short* slot, int tid)
{
#pragma unroll
    for (int s = 0; s < 3; ++s)
#pragma unroll
        for (int v = 0; v < 2; ++v) {
            int e = v * 512 + tid;     // 0..1023 = 128 rows x 8 units
            gl16(Ag + (size_t)(e >> 3) * KP_PRE + s * 640 + kr * 64 + (e & 7) * 8,
                 slot + s * 8192 + e * 8);
        }
#pragma unroll
    for (int s = 0; s < 3; ++s) {
        int e = tid;                   // 0..511 = 64 rows x 8 units
        gl16(Bg + (size_t)(e >> 3) * KP_PRE + s * 640 + kr * 64 + (e & 7) * 8,
             slot + 24576 + s * 4096 + e * 8);
    }
}

// z-path staging, 512-thread variant: one gl16 per split per thread
__device__ __forceinline__ void stageA3w(const unsigned short* Ag, int kr,
                                         unsigned short* buf, int tid)
{
#pragma unroll
    for (int s = 0; s < 3; ++s) {
        int e = tid;   // 0..511 = 64 rows x 8 units
        gl16(Ag + (size_t)(e >> 3) * KP_HS + (s * 8 + kr) * 64 + (e & 7) * 8,
             buf + s * 4096 + e * 8);
    }
}
__device__ __forceinline__ void stageB3w(const unsigned short* Bg, int kr,
                                         unsigned short* buf, int tid)
{
#pragma unroll
    for (int s = 0; s < 3; ++s) {
        int e = tid;
        gl16(Bg + (size_t)(e >> 3) * KP_HS + (s * 8 + kr) * 64 + (e & 7) * 8,
             buf + 12288 + s * 4096 + e * 8);
    }
}
__device__ __forceinline__ void stage6w(const unsigned short* Ag,
                                        const unsigned short* Bg,
                                        int kr, unsigned short* buf, int tid)
{
    stageA3w(Ag, kr, buf, tid);
    stageB3w(Bg, kr, buf, tid);
}

// ---------------- merged builder (coalesced Wk/Rk reads via LDS transpose) ---
__global__ __launch_bounds__(256) void build_all(const float* __restrict__ fp,
                                                 const float* __restrict__ gt,
                                                 const float* __restrict__ Wk,
                                                 const float* __restrict__ Rk,
                                                 const float* __restrict__ sw,
                                                 const float* __restrict__ bias)
{
    __shared__ float lds_f[16][256];               // 16 KB transpose tile
    const int b = blockIdx.x, tid = threadIdx.x;
    if (b < 5120) {                                   // ---- build_Xb ----
        const int bx = b & 1023, by = b >> 10;
        const int m  = bx * 16 + (tid >> 4);
        const int k8 = (by * 16 + (tid & 15)) * 8;
        const int t = m >> 9, bb = m & 511;
        float x[8];
        if (k8 < 512) {
            float4 v0 = *(const float4*)(fp + ((size_t)(bb * 32 + t)) * 512 + k8);
            float4 v1 = *(const float4*)(fp + ((size_t)(bb * 32 + t)) * 512 + k8 + 4);
            x[0]=v0.x; x[1]=v0.y; x[2]=v0.z; x[3]=v0.w;
            x[4]=v1.x; x[5]=v1.y; x[6]=v1.z; x[7]=v1.w;
        } else if (t > 0) {
            float4 v0 = *(const float4*)(gt + ((size_t)(bb * 32 + t - 1)) * 128 + (k8 - 512));
            float4 v1 = *(const float4*)(gt + ((size_t)(bb * 32 + t - 1)) * 128 + (k8 - 512) + 4);
            x[0]=v0.x; x[1]=v0.y; x[2]=v0.z; x[3]=v0.w;
            x[4]=v1.x; x[5]=v1.y; x[6]=v1.z; x[7]=v1.w;
        } else {
#pragma unroll
            for (int j = 0; j < 8; ++j) x[j] = 0.f;
        }
        unsigned short s0[8], s1[8], s2[8];
#pragma unroll
        for (int j = 0; j < 8; ++j) split3(x[j], s0[j], s1[j], s2[j]);
        const int u = (k8 >> 3) & 7;
        const int base = (k8 & ~63) + (((u ^ (m & 7))) << 3);
        ushort8v v0, v1, v2;
#pragma unroll
        for (int j = 0; j < 8; ++j) { v0[j] = s0[j]; v1[j] = s1[j]; v2[j] = s2[j]; }
        *(ushort8v*)&g_Xb[m][0 * 640 + base] = v0;
        *(ushort8v*)&g_Xb[m][1 * 640 + base] = v1;
        *(ushort8v*)&g_Xb[m][2 * 640 + base] = v2;
    } else if (b < 5440) {                  // ---- build_Wb (coalesced) ----
        const int ib = b - 5120;            // 320 blocks: 40 k-groups x 8 n-chunks
        const int k0  = (ib >> 3) * 16;     // 16 k-rows
        const int n0c = (ib & 7) * 256;     // 256 n-cols
#pragma unroll
        for (int r = 0; r < 16; ++r)
            lds_f[r][tid] = Wk[(size_t)(k0 + r) * 2048 + n0c + tid];
        __syncthreads();
        const int n  = n0c + tid;
        const int np = ((n & 511) << 2) | (n >> 9);
#pragma unroll
        for (int g = 0; g < 2; ++g) {
            const int k8 = k0 + g * 8;
            float x[8];
#pragma unroll
            for (int j = 0; j < 8; ++j) x[j] = lds_f[g * 8 + j][tid];
            unsigned short s0[8], s1[8], s2[8];
#pragma unroll
            for (int j = 0; j < 8; ++j) split3(x[j], s0[j], s1[j], s2[j]);
            const int u = (k8 >> 3) & 7;
            const int base = (k8 & ~63) + (((u ^ (np & 7))) << 3);
            ushort8v v0, v1, v2;
#pragma unroll
            for (int j = 0; j < 8; ++j) { v0[j] = s0[j]; v1[j] = s1[j]; v2[j] = s2[j]; }
            *(ushort8v*)&g_Wb[np][0 * 640 + base] = v0;
            *(ushort8v*)&g_Wb[np][1 * 640 + base] = v1;
            *(ushort8v*)&g_Wb[np][2 * 640 + base] = v2;
        }
    } else if (b < 5696) {                  // ---- build_Rb (coalesced) ----
        const int ib = b - 5440;            // 256 blocks: 32 k-groups x 8 n-chunks
        const int k0  = (ib >> 3) * 16;
        const int n0c = (ib & 7) * 256;
#pragma unroll
        for (int r = 0; r < 16; ++r)
            lds_f[r][tid] = Rk[(size_t)(k0 + r) * 2048 + n0c + tid];
        __syncthreads();
        const int n  = n0c + tid;
        const int np = ((n & 511) << 2) | (n >> 9);
#pragma unroll
        for (int g = 0; g < 2; ++g) {
            const int k8 = k0 + g * 8;
            float x[8];
#pragma unroll
            for (int j = 0; j < 8; ++j) x[j] = lds_f[g * 8 + j][tid];
            unsigned short s0[8], s1[8], s2[8];
#pragma unroll
            for (int j = 0; j < 8; ++j) split3(x[j], s0[j], s1[j], s2[j]);
            const int u = (k8 >> 3) & 7;
            const int base = (k8 & ~63) + (((u ^ (np & 7))) << 3);
            ushort8v v0, v1, v2;
#pragma unroll
            for (int j = 0; j < 8; ++j) { v0[j] = s0[j]; v1[j] = s1[j]; v2[j] = s2[j]; }
            *(ushort8v*)&g_Rb[np][0 * 512 + base] = v0;
            *(ushort8v*)&g_Rb[np][1 * 512 + base] = v1;
            *(ushort8v*)&g_Rb[np][2 * 512 + base] = v2;
        }
    } else if (b < 5960) {                            // ---- build_misc ----
        int id = (b - 5696) * 256 + tid;
        if (id < 128 * 512) {
            int c = id >> 9, r = id & 511;
            g_swT[c][r] = sw[(size_t)r * 128 + c];
        } else if (id < 128 * 512 + 2048) {
            int np = id - 128 * 512;
            g_bperm[np] = bias[(np & 3) * 512 + (np >> 2)];
        }
    } else {                                          // ---- init counters ----
        if (tid < 8) { g_xcnt[tid * 16] = 0u; g_xrel[tid * 16] = 0u; }
    }
}

// ---------------- PRE: persistent, continuous 160-chunk ring (R13) -----------
__global__ __launch_bounds__(512, 1) void pre_mfma()
{
    __shared__ __align__(16) char smem[147456];    // 2 slots x 72 KB
    const int tid = threadIdx.x, lane = tid & 63, wave = tid >> 6;   // 8 waves
    const int bi = blockIdx.x;                      // 0..255
    const int x8 = bi & 7, r = bi >> 3;             // XCD, 0..31
    const int M  = x8 + 8 * (r >> 1);               // m-row 0..127 (XCD-local)
    const int half = r & 1;                         // n-half: tiles 0-15 / 16-31
    const int m0 = M * 128;
    const int wr = wave >> 2, wc = wave & 3, l15 = lane & 15, ql = lane >> 4;
    unsigned short* ring = (unsigned short*)smem;
    const unsigned short* Ag = &g_Xb[m0][0];

    constexpr int ipt[6] = {0, 0, 1, 0, 1, 2};
    constexpr int jpt[6] = {0, 1, 0, 2, 1, 0};

    f32x4 acc[4];

    // chunk c = tile*10 + kr, c in [0,160)
    stage_pre(Ag, &g_Wb[(half * 16 + 0) * 64][0], 0, ring + 0 * 36864, tid);
    stage_pre(Ag, &g_Wb[(half * 16 + 0) * 64][0], 1, ring + 1 * 36864, tid);
    for (int c = 0; c < 160; ++c) {
        const int kr = c - (c / 10) * 10;           // c % 10
        const int tile = c / 10;
        const int n0 = (half * 16 + tile) * 64;
        if (kr == 0) {
#pragma unroll
            for (int a = 0; a < 4; ++a) acc[a] = (f32x4){0.f, 0.f, 0.f, 0.f};
        }
        if (c < 159) WAITV(9);       // next chunk's 9 loads stay in flight
        else         WAITV(0);
        SBAR();
        const unsigned short* Ab = ring + (c & 1) * 36864;
        const unsigned short* Bb = Ab + 24576;
#pragma unroll
        for (int sub = 0; sub < 2; ++sub) {
            const int uw = sub * 4 + ql;
            short8v a0[4], a1[4], a2[4], b0, b1, b2;
#pragma unroll
            for (int fa = 0; fa < 4; ++fa) {
                a0[fa] = fragld(Ab + 0 * 8192, wr * 64 + fa * 16 + l15, uw);
                a1[fa] = fragld(Ab + 1 * 8192, wr * 64 + fa * 16 + l15, uw);
                a2[fa] = fragld(Ab + 2 * 8192, wr * 64 + fa * 16 + l15, uw);
            }
            b0 = fragld(Bb + 0 * 4096, wc * 16 + l15, uw);
            b1 = fragld(Bb + 1 * 4096, wc * 16 + l15, uw);
            b2 = fragld(Bb + 2 * 4096, wc * 16 + l15, uw);
#pragma unroll
            for (int p = 0; p < 6; ++p) {
                const short8v* A2 = (ipt[p] == 0) ? a0 : ((ipt[p] == 1) ? a1 : a2);
                const short8v  B2 = (jpt[p] == 0) ? b0 : ((jpt[p] == 1) ? b1 : b2);
#pragma unroll
                for (int fa = 0; fa < 4; ++fa)
                    acc[fa] = __builtin_amdgcn_mfma_f32_16x16x32_bf16(
                        A2[fa], B2, acc[fa], 0, 0, 0);
            }
        }
        SBAR();   // all waves done reading slot before restaging it
        if (c + 2 < 160) {
            const int c2 = c + 2;
            const int t2 = c2 / 10;
            stage_pre(Ag, &g_Wb[(half * 16 + t2) * 64][0], c2 - t2 * 10,
                      ring + (c2 & 1) * 36864, tid);
        }
        if (kr == 9) {
#pragma unroll
            for (int fa = 0; fa < 4; ++fa) {
                const int np = n0 + wc * 16 + l15;
                const float bv = g_bperm[np];
#pragma unroll
                for (int q = 0; q < 4; ++q) {
                    const int m = m0 + wr * 64 + fa * 16 + ql * 4 + q;
                    g_pre[m][np] = acc[fa][q] + bv;
                }
            }
        }
    }
}

// ---------------- persistent recurrence (R8/R12 verbatim: XCD-local, 512t) ---
__global__ __launch_bounds__(512, 1) void charnn_rec(
    const float* __restrict__ sb,
    float* __restrict__ seq, float* __restrict__ out_h, float* __restrict__ out_c)
{
    __shared__ __align__(16) char smem[147456];    // 3 ring bufs x 48 KB; zbuf alias
    float (*zbuf)[68] = (float (*)[68])smem;       // 17 KB, inside slot0 A-half
    unsigned short* ring = (unsigned short*)smem;

    const int bi = blockIdx.x, tid = threadIdx.x;
    const int lane = tid & 63, wave = tid >> 6;    // wave 0..7
    const int x  = bi & 7, jj = bi >> 3;
    const int Mg = x;                                // == XCD id
    const int Ng = jj;                               // 0..31
    const int m0 = Mg * 64, n0 = Ng * 64;
    const int wr = wave >> 2, wc = wave & 3, l15 = lane & 15, ql = lane >> 4;

    const int m_e = tid >> 3;            // 0..63
    const int rb2 = (tid & 7) * 2;       // 0,2,..,14
    const int mg = m0 + m_e;
    float cst[2] = {0.f, 0.f};

    const int rgrp = Mg * 4 + (jj & 3);
    const int cg   = jj >> 2;
    const int arow = Mg * 64 + jj * 2;
    const bool xleader = (jj == 0);

    constexpr int ipt[6] = {0, 0, 1, 0, 1, 2};
    constexpr int jpt[6] = {0, 1, 0, 2, 1, 0};

    const unsigned short* Bg = &g_Rb[n0][0];

    f32x4 pqa, pqb;
    {
        const float* prow = &g_pre[0 * 512 + mg][n0];
        pqa = *(const f32x4*)(prow + rb2 * 4);
        pqb = *(const f32x4*)(prow + rb2 * 4 + 4);
    }

    for (int ph = 0; ph < 34; ++ph) {
        const int t = ph;
        const bool do_z = (ph >= 1 && ph <= 31);

        const unsigned short* Ag = nullptr;
        if (do_z) {
            Ag = &g_hs[(t + 1) & 1][m0][0];
            stageA3w(Ag, 0, ring + 0 * 24576, tid);
            stageA3w(Ag, 1, ring + 1 * 24576, tid);
            stageA3w(Ag, 2, ring + 2 * 24576, tid);
        }

        if (ph >= 1 && ph <= 32 && tid < 256) {
            const int tl = ph - 1;
            const int row = rgrp * 16 + (tid >> 4);
            const int col = cg * 16 + (tid & 15);
            const float* hrow = &g_hf[tl & 1][(size_t)row * 512];
            const float* wcol = &g_swT[col][0];
            float s0 = sb[col], s1 = 0.f, s2 = 0.f, s3 = 0.f;
#pragma unroll 8
            for (int k = 0; k < 512; k += 4) {
                float4 hv = *(const float4*)(hrow + k);
                float4 wv = *(const float4*)(wcol + k);
                s0 = fmaf(hv.x, wv.x, s0); s1 = fmaf(hv.y, wv.y, s1);
                s2 = fmaf(hv.z, wv.z, s2); s3 = fmaf(hv.w, wv.w, s3);
            }
            float bv = (s0 + s1) + (s2 + s3); int bidx = col;
#pragma unroll
            for (int m = 1; m < 16; m <<= 1) {
                float ov = __shfl_xor(bv, m, 64);
                int   oi = __shfl_xor(bidx, m, 64);
                if (ov > bv || (ov == bv && oi < bidx)) { bv = ov; bidx = oi; }
            }
            if ((tid & 15) == 0) {
                g_plv[tl & 1][row * 8 + cg] = bv;
                g_pli[tl & 1][row * 8 + cg] = bidx;
            }
        }

        if (ph >= 2 && wave < 2) {
            const int t2 = ph - 2;
            const int row = arow + wave;
            float v; int idx;
            if (lane < 8) {
                v   = g_plv[t2 & 1][row * 8 + lane];
                idx = g_pli[t2 & 1][row * 8 + lane];
            } else { v = -INFINITY; idx = 0x7fffffff; }
#pragma unroll
            for (int m = 1; m < 8; m <<= 1) {
                float ov = __shfl_xor(v, m, 64);
                int   oi = __shfl_xor(idx, m, 64);
                if (ov > v || (ov == v && oi < idx)) { v = ov; idx = oi; }
            }
            int win = __shfl(idx, 0, 64);
            if (lane < 32) {
                int c4 = lane * 4;
                float4 o;
                o.x = (c4 + 0 == win) ? 1.f : 0.f;
                o.y = (c4 + 1 == win) ? 1.f : 0.f;
                o.z = (c4 + 2 == win) ? 1.f : 0.f;
                o.w = (c4 + 3 == win) ? 1.f : 0.f;
                *(float4*)(seq + ((size_t)row * 32 + t2) * 128 + c4) = o;
            }
        }

        if (ph <= 31) {
            if (do_z) {
                f32x4 acc[2];
                acc[0] = (f32x4){0.f, 0.f, 0.f, 0.f};
                acc[1] = (f32x4){0.f, 0.f, 0.f, 0.f};
#pragma unroll
                for (int kr = 0; kr < 8; ++kr) {
                    if (kr >= 1 && kr <= 5)
                        stage6w(Ag, Bg, kr + 2, ring + ((kr + 2) % 3) * 24576, tid);
                    if      (kr == 0) WAITV(6);
                    else if (kr == 1) WAITV(9);
                    else if (kr == 6) WAITV(6);
                    else if (kr == 7) WAITV(0);
                    else              WAITV(12);
                    SBAR();
                    const unsigned short* Ab = ring + (kr % 3) * 24576;
                    const unsigned short* Bb = Ab + 12288;
#pragma unroll
                    for (int sub = 0; sub < 2; ++sub) {
                        const int uw = sub * 4 + ql;
                        short8v a0[2], a1[2], a2[2], b0, b1, b2;
                        a0[0] = fragld(Ab + 0 * 4096, wr * 32 + l15, uw);
                        a0[1] = fragld(Ab + 0 * 4096, wr * 32 + 16 + l15, uw);
                        a1[0] = fragld(Ab + 1 * 4096, wr * 32 + l15, uw);
                        a1[1] = fragld(Ab + 1 * 4096, wr * 32 + 16 + l15, uw);
                        a2[0] = fragld(Ab + 2 * 4096, wr * 32 + l15, uw);
                        a2[1] = fragld(Ab + 2 * 4096, wr * 32 + 16 + l15, uw);
                        b0 = fragld(Bb + 0 * 4096, wc * 16 + l15, uw);
                        b1 = fragld(Bb + 1 * 4096, wc * 16 + l15, uw);
                        b2 = fragld(Bb + 2 * 4096, wc * 16 + l15, uw);
#pragma unroll
                        for (int p = 0; p < 6; ++p) {
                            const short8v* A2 = (ipt[p] == 0) ? a0 :
                                                ((ipt[p] == 1) ? a1 : a2);
                            const short8v  B2 = (jpt[p] == 0) ? b0 :
                                                ((jpt[p] == 1) ? b1 : b2);
                            acc[0] = __builtin_amdgcn_mfma_f32_16x16x32_bf16(
                                A2[0], B2, acc[0], 0, 0, 0);
                            acc[1] = __builtin_amdgcn_mfma_f32_16x16x32_bf16(
                                A2[1], B2, acc[1], 0, 0, 0);
                        }
                    }
                }
                __syncthreads();   // drain ring reads; ring -> zbuf reuse safe
#pragma unroll
                for (int fa = 0; fa < 2; ++fa)
#pragma unroll
                    for (int q2 = 0; q2 < 4; ++q2)
                        zbuf[wr * 32 + fa * 16 + ql * 4 + q2]
                            [wc * 16 + l15] = acc[fa][q2];
            }
            __syncthreads();

            unsigned short hs0[2], hs1[2], hs2[2];
            float hv2[2];
#pragma unroll
            for (int i = 0; i < 2; ++i) {
                const int rl = rb2 + i;
                float zi, zf, zg, zo;
                if (t > 0) {
                    float4 zq = *(const float4*)&zbuf[m_e][rl * 4];
                    zi = zq.x; zf = zq.y; zg = zq.z; zo = zq.w;
                } else { zi = zf = zg = zo = 0.f; }
                f32x4 pq = (i == 0) ? pqa : pqb;
                zi += pq[0]; zf += pq[1]; zg += pq[2]; zo += pq[3];
                float c2 = sigf(zf) * cst[i] + sigf(zi) * tanhf(zg);
                float h2 = sigf(zo) * tanhf(c2);
                cst[i] = c2;
                hv2[i] = h2;
                split3(h2, hs0[i], hs1[i], hs2[i]);
            }
            const int r0g = Ng * 16 + rb2;
            *(float2*)&g_hf[t & 1][(size_t)mg * 512 + r0g] =
                make_float2(hv2[0], hv2[1]);
            if (t == 31) {
                *(float2*)&out_h[(size_t)mg * 512 + r0g] =
                    make_float2(hv2[0], hv2[1]);
                *(float2*)&out_c[(size_t)mg * 512 + r0g] =
                    make_float2(cst[0], cst[1]);
            }
            const int su = ((r0g >> 3) & 7) ^ (mg & 7);
            const int abase = (r0g & ~63) + (su << 3) + (r0g & 7);
#pragma unroll
            for (int i = 0; i < 3; ++i) {
                ushort2v v;
#pragma unroll
                for (int j = 0; j < 2; ++j)
                    v[j] = (i == 0) ? hs0[j] : ((i == 1) ? hs1[j] : hs2[j]);
                *(ushort2v*)&g_hs[t & 1][mg][i * 512 + abase] = v;
            }
        }

        if (ph < 33) {
            __syncthreads();

            if (ph <= 30) {
                stageB3w(Bg, 0, ring + 0 * 24576, tid);
                stageB3w(Bg, 1, ring + 1 * 24576, tid);
                stageB3w(Bg, 2, ring + 2 * 24576, tid);
                const float* prow = &g_pre[(ph + 1) * 512 + mg][n0];
                pqa = *(const f32x4*)(prow + rb2 * 4);
                pqb = *(const f32x4*)(prow + rb2 * 4 + 4);
            }

            if (tid == 0) {
                __hip_atomic_fetch_add(&g_xcnt[x * 16], 1u,
                                       __ATOMIC_RELAXED, __HIP_MEMORY_SCOPE_AGENT);
                if (xleader) {
                    const unsigned xt = 32u * (unsigned)(ph + 1);
                    while (__hip_atomic_load(&g_xcnt[x * 16], __ATOMIC_RELAXED,
                                             __HIP_MEMORY_SCOPE_AGENT) < xt)
                        __builtin_amdgcn_s_sleep(2);
                    __hip_atomic_store(&g_xrel[x * 16], (unsigned)(ph + 1),
                                       __ATOMIC_RELAXED, __HIP_MEMORY_SCOPE_AGENT);
                }
                while (__hip_atomic_load(&g_xrel[x * 16], __ATOMIC_RELAXED,
                                         __HIP_MEMORY_SCOPE_AGENT) < (unsigned)(ph + 1))
                    __builtin_amdgcn_s_sleep(2);
                __builtin_amdgcn_fence(__ATOMIC_ACQUIRE, "agent");
            }
            __syncthreads();
        }
    }
}

// ---------------------------------------------------------------------------
extern "C" void kernel_launch(void* const* d_in, const int* in_sizes, int n_in,
                              void* d_out, int out_size, void* d_ws, size_t ws_size,
                              hipStream_t stream)
{
    const float* fp   = (const float*)d_in[0];  // f_pool       [512,32,512]
    const float* gt   = (const float*)d_in[1];  // ground_truth [512,32,128]
    const float* Wk   = (const float*)d_in[2];  // kernel       [640,2048]
    const float* Rk   = (const float*)d_in[3];  // rec_kernel   [512,2048]
    const float* bias = (const float*)d_in[4];  // [2048]
    const float* sw   = (const float*)d_in[5];  // softmax_w    [512,128]
    const float* sb   = (const float*)d_in[6];  // softmax_b    [128]
    float* seq   = (float*)d_out;                        // [512,32,128]
    float* out_h = seq + (size_t)512 * 32 * 128;         // [512,512]
    float* out_c = out_h + (size_t)512 * 512;            // [512,512]

    hipLaunchKernelGGL(build_all, dim3(5961), dim3(256), 0, stream,
                       fp, gt, Wk, Rk, sw, bias);
    hipLaunchKernelGGL(pre_mfma, dim3(256), dim3(512), 0, stream);
    hipLaunchKernelGGL(charnn_rec, dim3(256), dim3(512), 0, stream,
                       sb, seq, out_h, out_c);
}